// Round 12
// baseline (471.562 us; speedup 1.0000x reference)
//
#include <hip/hip_runtime.h>
#include <hip/hip_bf16.h>

typedef unsigned short u16;
typedef unsigned int u32;

typedef short short8 __attribute__((ext_vector_type(8)));
typedef float f32x4 __attribute__((ext_vector_type(4)));

// ---------------- problem constants ----------------
constexpr int Bc   = 8;
constexpr int Nc   = 2048;
constexpr int DIMc = 1024;
constexpr int Ec   = 8;
constexpr int HIDc = 2048;
constexpr int CAPc = 512;
constexpr int NTOK   = Bc * Nc;        // 16384
constexpr int SLOTPE = Bc * CAPc;      // 4096 slots per expert
constexpr int NSLOT  = Ec * SLOTPE;    // 32768

// ---------------- misc block layout (relative offsets, 2 MiB) ----------------
constexpr size_t OFF_SLOTTOK = 0;
constexpr size_t OFF_SGATE   = OFF_SLOTTOK + (size_t)NSLOT * 4;
constexpr size_t OFF_G1      = OFF_SGATE + (size_t)NSLOT * 4;
constexpr size_t OFF_G2      = OFF_G1 + (size_t)NTOK * 4;
constexpr size_t OFF_META    = OFF_G2 + (size_t)NTOK * 4;
constexpr size_t OFF_S1      = OFF_META + (size_t)NTOK * 4;
constexpr size_t OFF_S2      = OFF_S1 + (size_t)NTOK * 4;
constexpr size_t OFF_RAW     = OFF_S2 + (size_t)NTOK * 4;
constexpr size_t OFF_S       = OFF_RAW + (size_t)NTOK * 8 * 4;
constexpr size_t OFF_C       = OFF_S + 64 * 4;
constexpr size_t MISC_SZ     = 2 << 20;
static_assert(OFF_C + 64 * 4 <= MISC_SZ, "misc overflow");

constexpr size_t SZ_W1T_E = (size_t)HIDc * DIMc * 2;    // 4 MiB
constexpr size_t SZ_W2T_E = (size_t)DIMc * HIDc * 2;    // 4 MiB
constexpr size_t SZ_EI_E  = (size_t)SLOTPE * DIMc * 2;  // 8 MiB
constexpr size_t SZ_HID_E = (size_t)SLOTPE * HIDc * 2;  // 16 MiB
constexpr size_t SZ_EO    = (size_t)NSLOT * DIMc * 2;   // 64 MiB (full, all experts)

// layout: eo[0,64M) | per-round {w1T, w2T, ei, hid} | misc
__device__ __host__ inline size_t layout_need(int epr) {
    return SZ_EO + (size_t)epr * (SZ_W1T_E + SZ_W2T_E + SZ_EI_E + SZ_HID_E) + MISC_SZ;
}

// ---------------- helpers ----------------
__device__ inline u16 f2bf(float f) {
    u32 u = __float_as_uint(f);
    u32 r = (u + 0x7fffu + ((u >> 16) & 1u)) >> 16;
    return (u16)r;
}
__device__ inline u32 pack2(float lo, float hi) {
    return (u32)f2bf(lo) | ((u32)f2bf(hi) << 16);
}
__device__ inline float bflo(u32 u) { return __uint_as_float(u << 16); }
__device__ inline float bfhi(u32 u) { return __uint_as_float(u & 0xffff0000u); }

// tanh-approx gelu via exp2 (max abs err ~1e-3)
__device__ inline float gelu_fast(float v) {
    const float u = v * (0.7978845608028654f + 0.0356774081363001f * v * v);
    return v / (1.f + __builtin_exp2f(-2.885390081777927f * u));
}

#define GLDS16(gp, lp)                                                          \
    __builtin_amdgcn_global_load_lds(                                          \
        (const __attribute__((address_space(1))) void*)(gp),                   \
        (__attribute__((address_space(3))) void*)(lp), 16, 0, 0)

// ---------------- init slot map ----------------
__global__ __launch_bounds__(256) void init_slots_kernel(int* __restrict__ slot_token) {
    int i = (blockIdx.x * 256 + threadIdx.x) * 4;
    slot_token[i] = -1; slot_token[i + 1] = -1; slot_token[i + 2] = -1; slot_token[i + 3] = -1;
}

// ---------------- gating: one wave per token ----------------
__global__ __launch_bounds__(256) void gate_kernel(
    const float* __restrict__ x, const float* __restrict__ wg,
    const float* __restrict__ rp, float* __restrict__ raw_out,
    float* __restrict__ g1_out, float* __restrict__ g2_out, int* __restrict__ meta_out)
{
    const int tk   = blockIdx.x * 4 + (threadIdx.x >> 6);
    const int lane = threadIdx.x & 63;
    const float* xr = x + (size_t)tk * DIMc;

    float acc[8] = {0.f, 0.f, 0.f, 0.f, 0.f, 0.f, 0.f, 0.f};
#pragma unroll
    for (int i = 0; i < 4; ++i) {
        const int d0 = i * 256 + lane * 4;
        float4 xv = *(const float4*)(xr + d0);
#pragma unroll
        for (int j = 0; j < 4; ++j) {
            float xs = (&xv.x)[j];
            float4 w0 = *(const float4*)(wg + (size_t)(d0 + j) * 8);
            float4 w1 = *(const float4*)(wg + (size_t)(d0 + j) * 8 + 4);
            acc[0] += xs * w0.x; acc[1] += xs * w0.y; acc[2] += xs * w0.z; acc[3] += xs * w0.w;
            acc[4] += xs * w1.x; acc[5] += xs * w1.y; acc[6] += xs * w1.z; acc[7] += xs * w1.w;
        }
    }
#pragma unroll
    for (int e = 0; e < 8; ++e) {
#pragma unroll
        for (int off = 1; off < 64; off <<= 1) acc[e] += __shfl_xor(acc[e], off);
    }

    if (lane == 0) {
        float mx = acc[0];
#pragma unroll
        for (int e = 1; e < 8; ++e) mx = fmaxf(mx, acc[e]);
        float ex[8], s = 0.f;
#pragma unroll
        for (int e = 0; e < 8; ++e) { ex[e] = expf(acc[e] - mx); s += ex[e]; }
        float inv = 1.f / s;
        float raw[8];
#pragma unroll
        for (int e = 0; e < 8; ++e) raw[e] = ex[e] * inv;

        int i1 = 0; float g1 = raw[0];
#pragma unroll
        for (int e = 1; e < 8; ++e) if (raw[e] > g1) { g1 = raw[e]; i1 = e; }
        int i2 = -1; float g2 = -1.f;
#pragma unroll
        for (int e = 0; e < 8; ++e) if (e != i1 && raw[e] > g2) { g2 = raw[e]; i2 = e; }

        float denom = g1 + g2 + 1e-9f;
        float g1n = g1 / denom, g2n = g2 / denom;
        int keep = (rp[tk] < (g2n / 0.2f)) ? 1 : 0;

        float* ro = raw_out + (size_t)tk * 8;
#pragma unroll
        for (int e = 0; e < 8; ++e) ro[e] = raw[e];
        g1_out[tk] = g1n;
        g2_out[tk] = g2n;
        meta_out[tk] = i1 | (i2 << 4) | (keep << 8);
    }
}

// ---------------- per-batch capacity scan (emits slot maps both ways) ----------------
__global__ __launch_bounds__(256) void scan_kernel(
    const int* __restrict__ meta, const float* __restrict__ g1, const float* __restrict__ g2,
    int* __restrict__ slot_token, int* __restrict__ slot1, int* __restrict__ slot2)
{
    const int b = blockIdx.x;
    const int t = threadIdx.x;
    __shared__ int cnt[256][8];
    __shared__ int base_e[8];

    int m[8];
#pragma unroll
    for (int i = 0; i < 8; ++i) m[i] = meta[b * Nc + t * 8 + i];

    int c[8] = {0, 0, 0, 0, 0, 0, 0, 0};
#pragma unroll
    for (int i = 0; i < 8; ++i) c[m[i] & 15]++;
#pragma unroll
    for (int e = 0; e < 8; ++e) cnt[t][e] = c[e];
    __syncthreads();
    if (t < 8) {
        int run = 0;
        for (int i = 0; i < 256; ++i) { int v = cnt[i][t]; cnt[i][t] = run; run += v; }
        base_e[t] = run < CAPc ? run : CAPc;
    }
    __syncthreads();
#pragma unroll
    for (int e = 0; e < 8; ++e) c[e] = cnt[t][e];
#pragma unroll
    for (int i = 0; i < 8; ++i) {
        const int tk = b * Nc + t * 8 + i;
        const int e = m[i] & 15;
        const int pos = c[e]++;
        if (pos < CAPc) {
            const int slot = ((e * Bc + b) << 9) | pos;
            slot_token[slot] = tk;
            slot1[tk] = slot;
        } else {
            slot1[tk] = -1;
        }
    }
    __syncthreads();

#pragma unroll
    for (int e = 0; e < 8; ++e) c[e] = 0;
#pragma unroll
    for (int i = 0; i < 8; ++i) {
        if ((m[i] >> 8) & 1) c[(m[i] >> 4) & 15]++;
    }
#pragma unroll
    for (int e = 0; e < 8; ++e) cnt[t][e] = c[e];
    __syncthreads();
    if (t < 8) {
        int run = 0;
        for (int i = 0; i < 256; ++i) { int v = cnt[i][t]; cnt[i][t] = run; run += v; }
    }
    __syncthreads();
#pragma unroll
    for (int e = 0; e < 8; ++e) c[e] = cnt[t][e];
#pragma unroll
    for (int i = 0; i < 8; ++i) {
        const int tk = b * Nc + t * 8 + i;
        int s2v = -1;
        if ((m[i] >> 8) & 1) {
            const int e = (m[i] >> 4) & 15;
            const int pos = base_e[e] + c[e]++;
            if (pos < CAPc) {
                const int slot = ((e * Bc + b) << 9) | pos;
                slot_token[slot] = tk;
                s2v = slot;
            }
        }
        slot2[tk] = s2v;
    }
}

// ---------------- loss reduction ----------------
__global__ __launch_bounds__(256) void reduce_stats_kernel(
    const float* __restrict__ raw, const int* __restrict__ meta,
    float* __restrict__ S, float* __restrict__ C)
{
    const int be = blockIdx.x, b = be >> 3, e = be & 7;
    float s = 0.f, c = 0.f;
    for (int n = threadIdx.x; n < Nc; n += 256) {
        const int tk = b * Nc + n;
        s += raw[(size_t)tk * 8 + e];
        c += ((meta[tk] & 15) == e) ? 1.f : 0.f;
    }
    __shared__ float sh_s[4], sh_c[4];
    const int lane = threadIdx.x & 63, wv = threadIdx.x >> 6;
#pragma unroll
    for (int off = 32; off; off >>= 1) { s += __shfl_down(s, off); c += __shfl_down(c, off); }
    if (lane == 0) { sh_s[wv] = s; sh_c[wv] = c; }
    __syncthreads();
    if (threadIdx.x == 0) {
        S[be] = sh_s[0] + sh_s[1] + sh_s[2] + sh_s[3];
        C[be] = sh_c[0] + sh_c[1] + sh_c[2] + sh_c[3];
    }
}

__global__ void loss_kernel(const float* __restrict__ S, const float* __restrict__ C,
                            float* __restrict__ dst)
{
    float v = S[threadIdx.x] * C[threadIdx.x];
#pragma unroll
    for (int off = 32; off; off >>= 1) v += __shfl_down(v, off);
    if (threadIdx.x == 0) *dst = v * (0.01f / ((float)Nc * (float)Nc));
}

// ---------------- weight transpose + bf16 convert ----------------
template <int R, int C>
__global__ __launch_bounds__(256) void transpose_kernel(
    const float* __restrict__ w, u16* __restrict__ wT, const int e0)
{
    __shared__ float tile[32][33];
    const int ez = blockIdx.z;
    const int c0 = blockIdx.x * 32, r0 = blockIdx.y * 32;
    const float* src = w + (size_t)(e0 + ez) * R * C;
    u16* dst = wT + (size_t)ez * C * R;
    const int t = threadIdx.x;
#pragma unroll
    for (int i = 0; i < 4; ++i) {
        const int r = i * 8 + (t >> 5), cc = t & 31;
        tile[r][cc] = src[(size_t)(r0 + r) * C + c0 + cc];
    }
    __syncthreads();
#pragma unroll
    for (int i = 0; i < 4; ++i) {
        const int cc = i * 8 + (t >> 5), r = t & 31;
        dst[(size_t)(c0 + cc) * R + r0 + r] = f2bf(tile[r][cc]);
    }
}

// ---------------- gather tokens into expert-slot rows (bf16) ----------------
__global__ __launch_bounds__(256) void gather_kernel(
    const float* __restrict__ x, const int* __restrict__ slot_token,
    u16* __restrict__ ei, const int slot0)
{
    const int s = blockIdx.x * 4 + (threadIdx.x >> 6);
    const int lane = threadIdx.x & 63;
    const int tk = slot_token[slot0 + s];
    uint4* dst = (uint4*)(ei + ((size_t)s << 10)) + lane * 2;
    if (tk < 0) {
        uint4 z = {0u, 0u, 0u, 0u};
        dst[0] = z; dst[1] = z;
    } else {
        const float4* src = (const float4*)(x + ((size_t)tk << 10)) + lane * 4;
        float4 v0 = src[0], v1 = src[1], v2 = src[2], v3 = src[3];
        uint4 o0, o1;
        o0.x = pack2(v0.x, v0.y); o0.y = pack2(v0.z, v0.w);
        o0.z = pack2(v1.x, v1.y); o0.w = pack2(v1.z, v1.w);
        o1.x = pack2(v2.x, v2.y); o1.y = pack2(v2.z, v2.w);
        o1.z = pack2(v3.x, v3.y); o1.w = pack2(v3.z, v3.w);
        dst[0] = o0; dst[1] = o1;
    }
}

// ---------------- 256x128 BK=64 bf16 MFMA GEMM (2-phase, 3 blocks/CU) ----------------
// 4 waves (2Mx2N), per-wave 128x64 output (acc[8][4]). LDS 48 KiB single-buffered
// (A 256x64 + B 128x64). Per kk-half: 12 ds_read_b128 -> 32 MFMA (ratio 0.375).
// Slot-XOR swizzle (8-slot rows) + L2/XCD tile swizzle, both verified (0 conflicts).

template <int K, bool GELU>
__device__ inline void gemm_body(
    const u16* __restrict__ A, const u16* __restrict__ Bt, u16* __restrict__ Cc,
    const int nB, const int ldc)
{
    __shared__ u16 As[256 * 64];   // 32 KiB
    __shared__ u16 Bs[128 * 64];   // 16 KiB

    const int tid = threadIdx.x;
    const int wv = tid >> 6, lane = tid & 63;

    // ---- bijective tile swizzle (XCD chunk + GN=4 n-grouping) ----
    const int MT = gridDim.x;
    const int lin = blockIdx.y * MT + blockIdx.x;
    const int nb  = MT * gridDim.y;
    const int per = nb >> 3;
    const int sid = (lin & 7) * per + (lin >> 3);
    const int gsz = MT << 2;
    const int g   = sid / gsz;
    const int r   = sid - g * gsz;
    const int mt  = r >> 2;
    const int nt  = (g << 2) + (r & 3);

    const int m0 = mt * 256, n0 = nt * 128;
    const int e = mt >> 4;    // 16 m-tiles (4096 rows) per expert

    const int wr = wv >> 1, wc = wv & 1;
    const int lr = lane & 15, lk = lane >> 4;

    // staging: thread tid covers A rows rb+32p (p<8), B rows rb+32p (p<4),
    // phys slot tid&7; global col pre-swizzled: phys slot s holds logical s^(row&7)
    const int rb = tid >> 3;
    const int gc = (((tid & 7) ^ ((tid >> 3) & 7)) * 8);

    const u16* pa = A + (size_t)(m0 + rb) * K + gc;
    const u16* pb = Bt + ((size_t)e * nB + n0 + rb) * K + gc;

    u16* la = As + tid * 8;
    u16* lb = Bs + tid * 8;

    f32x4 acc[8][4];
#pragma unroll
    for (int i = 0; i < 8; ++i)
#pragma unroll
        for (int j = 0; j < 4; ++j) acc[i][j] = (f32x4)0.f;

    for (int k0 = 0; k0 < K; k0 += 64) {
        __syncthreads();
#pragma unroll
        for (int p = 0; p < 8; ++p)
            GLDS16(pa + (size_t)(32 * p) * K, la + p * 2048);
#pragma unroll
        for (int p = 0; p < 4; ++p)
            GLDS16(pb + (size_t)(32 * p) * K, lb + p * 2048);
        pa += 64; pb += 64;
        __syncthreads();

#pragma unroll
        for (int kk = 0; kk < 2; ++kk) {
            const int sl = ((kk * 4 + lk) ^ (lr & 7)) * 8;
            short8 a[8], b[4];
#pragma unroll
            for (int f = 0; f < 8; ++f)
                a[f] = *(const short8*)(As + (wr * 128 + f * 16 + lr) * 64 + sl);
#pragma unroll
            for (int f = 0; f < 4; ++f)
                b[f] = *(const short8*)(Bs + (wc * 64 + f * 16 + lr) * 64 + sl);
#pragma unroll
            for (int fm = 0; fm < 8; ++fm)
#pragma unroll
                for (int fn = 0; fn < 4; ++fn)
                    acc[fm][fn] = __builtin_amdgcn_mfma_f32_16x16x32_bf16(
                        a[fm], b[fn], acc[fm][fn], 0, 0, 0);
        }
    }

#pragma unroll
    for (int fm = 0; fm < 8; ++fm) {
        const int row = m0 + wr * 128 + fm * 16 + lk * 4;
#pragma unroll
        for (int fn = 0; fn < 4; ++fn) {
            const int col = n0 + wc * 64 + fn * 16 + lr;
#pragma unroll
            for (int r2 = 0; r2 < 4; ++r2) {
                float v = acc[fm][fn][r2];
                if (GELU) v = gelu_fast(v);
                Cc[(size_t)(row + r2) * ldc + col] = f2bf(v);
            }
        }
    }
}

__global__ __launch_bounds__(256, 3) void gemm1_kernel(
    const u16* __restrict__ A, const u16* __restrict__ Bt, u16* __restrict__ Cc)
{
    gemm_body<DIMc, true>(A, Bt, Cc, HIDc, HIDc);
}

__global__ __launch_bounds__(256, 3) void gemm2_kernel(
    const u16* __restrict__ A, const u16* __restrict__ Bt, u16* __restrict__ Cc)
{
    gemm_body<HIDc, false>(A, Bt, Cc, DIMc, DIMc);
}

// ---------------- combine: out[tk] = g1*eo[s1] + g2*eo[s2] (fully coalesced) ----------------
__global__ __launch_bounds__(256) void combine_kernel(
    const u16* __restrict__ eo, const int* __restrict__ slot1, const int* __restrict__ slot2,
    const float* __restrict__ g1, const float* __restrict__ g2, float* __restrict__ out)
{
    const int tk = blockIdx.x * 4 + (threadIdx.x >> 6);
    const int lane = threadIdx.x & 63;
    int s1 = slot1[tk], s2 = slot2[tk];
    const float a = (s1 >= 0) ? g1[tk] : 0.f;
    const float b = (s2 >= 0) ? g2[tk] : 0.f;
    if (s1 < 0) s1 = 0;
    if (s2 < 0) s2 = 0;
    const uint4* p1 = (const uint4*)(eo + ((size_t)s1 << 10)) + lane * 2;
    const uint4* p2 = (const uint4*)(eo + ((size_t)s2 << 10)) + lane * 2;
    uint4 x0 = p1[0], x1 = p1[1];
    uint4 y0 = p2[0], y1 = p2[1];
    float4* dst = (float4*)(out + ((size_t)tk << 10)) + lane * 4;
    float4 o;
    o.x = a * bflo(x0.x) + b * bflo(y0.x); o.y = a * bfhi(x0.x) + b * bfhi(y0.x);
    o.z = a * bflo(x0.y) + b * bflo(y0.y); o.w = a * bfhi(x0.y) + b * bfhi(y0.y);
    dst[0] = o;
    o.x = a * bflo(x0.z) + b * bflo(y0.z); o.y = a * bfhi(x0.z) + b * bfhi(y0.z);
    o.z = a * bflo(x0.w) + b * bflo(y0.w); o.w = a * bfhi(x0.w) + b * bfhi(y0.w);
    dst[1] = o;
    o.x = a * bflo(x1.x) + b * bflo(y1.x); o.y = a * bfhi(x1.x) + b * bfhi(y1.x);
    o.z = a * bflo(x1.y) + b * bflo(y1.y); o.w = a * bfhi(x1.y) + b * bfhi(y1.y);
    dst[2] = o;
    o.x = a * bflo(x1.z) + b * bflo(y1.z); o.y = a * bfhi(x1.z) + b * bfhi(y1.z);
    o.z = a * bflo(x1.w) + b * bflo(y1.w); o.w = a * bfhi(x1.w) + b * bfhi(y1.w);
    dst[3] = o;
}

// ---------------- launch ----------------
extern "C" void kernel_launch(void* const* d_in, const int* in_sizes, int n_in,
                              void* d_out, int out_size, void* d_ws, size_t ws_size,
                              hipStream_t stream)
{
    (void)in_sizes; (void)n_in; (void)out_size;

    const float* x  = (const float*)d_in[0];
    const float* wg = (const float*)d_in[1];
    const float* w1 = (const float*)d_in[2];
    const float* w2 = (const float*)d_in[3];
    const float* rp = (const float*)d_in[4];
    float* out = (float*)d_out;
    char* ws = (char*)d_ws;

    int epr = 4;
    while (epr > 1 && layout_need(epr) > ws_size) epr >>= 1;
    if (layout_need(epr) > ws_size) return;   // < 97 MiB: cannot run

    u16* eo  = (u16*)(ws);
    u16* w1T = (u16*)(ws + SZ_EO);
    u16* w2T = (u16*)(ws + SZ_EO + (size_t)epr * SZ_W1T_E);
    u16* ei  = (u16*)(ws + SZ_EO + (size_t)epr * (SZ_W1T_E + SZ_W2T_E));
    u16* hid = (u16*)(ws + SZ_EO + (size_t)epr * (SZ_W1T_E + SZ_W2T_E + SZ_EI_E));
    char* misc = ws + SZ_EO + (size_t)epr * (SZ_W1T_E + SZ_W2T_E + SZ_EI_E + SZ_HID_E);

    int* slot_token = (int*)(misc + OFF_SLOTTOK);
    float* g1 = (float*)(misc + OFF_G1);
    float* g2 = (float*)(misc + OFF_G2);
    int* meta = (int*)(misc + OFF_META);
    int* s1 = (int*)(misc + OFF_S1);
    int* s2 = (int*)(misc + OFF_S2);
    float* raw = (float*)(misc + OFF_RAW);
    float* Sr = (float*)(misc + OFF_S);
    float* C1 = (float*)(misc + OFF_C);

    init_slots_kernel<<<NSLOT / 1024, 256, 0, stream>>>(slot_token);
    gate_kernel<<<NTOK / 4, 256, 0, stream>>>(x, wg, rp, raw, g1, g2, meta);
    scan_kernel<<<Bc, 256, 0, stream>>>(meta, g1, g2, slot_token, s1, s2);
    reduce_stats_kernel<<<64, 256, 0, stream>>>(raw, meta, Sr, C1);
    loss_kernel<<<1, 64, 0, stream>>>(Sr, C1, out + (size_t)NTOK * DIMc);

    for (int e0 = 0; e0 < Ec; e0 += epr) {
        transpose_kernel<DIMc, HIDc><<<dim3(HIDc / 32, DIMc / 32, epr), 256, 0, stream>>>(
            w1, w1T, e0);
        transpose_kernel<HIDc, DIMc><<<dim3(DIMc / 32, HIDc / 32, epr), 256, 0, stream>>>(
            w2, w2T, e0);
        gather_kernel<<<epr * SLOTPE / 4, 256, 0, stream>>>(x, slot_token, ei, e0 * SLOTPE);

        gemm1_kernel<<<dim3(epr * 16, HIDc / 128), 256, 0, stream>>>(ei, w1T, hid);
        gemm2_kernel<<<dim3(epr * 16, DIMc / 128), 256, 0, stream>>>(
            hid, w2T, eo + (size_t)e0 * SLOTPE * DIMc);
    }

    combine_kernel<<<NTOK / 4, 256, 0, stream>>>(eo, s1, s2, g1, g2, out);
}

// Round 13
// 429.836 us; speedup vs baseline: 1.0971x; 1.0971x over previous
//
#include <hip/hip_runtime.h>
#include <hip/hip_bf16.h>

typedef unsigned short u16;
typedef unsigned int u32;

typedef short short8 __attribute__((ext_vector_type(8)));
typedef float f32x4 __attribute__((ext_vector_type(4)));

// ---------------- problem constants ----------------
constexpr int Bc   = 8;
constexpr int Nc   = 2048;
constexpr int DIMc = 1024;
constexpr int Ec   = 8;
constexpr int HIDc = 2048;
constexpr int CAPc = 512;
constexpr int NTOK   = Bc * Nc;        // 16384
constexpr int SLOTPE = Bc * CAPc;      // 4096 slots per expert
constexpr int NSLOT  = Ec * SLOTPE;    // 32768

// ---------------- misc block layout (relative offsets, 2 MiB) ----------------
constexpr size_t OFF_SLOTTOK = 0;
constexpr size_t OFF_G1      = OFF_SLOTTOK + (size_t)NSLOT * 4;
constexpr size_t OFF_G2      = OFF_G1 + (size_t)NTOK * 4;
constexpr size_t OFF_META    = OFF_G2 + (size_t)NTOK * 4;
constexpr size_t OFF_S1      = OFF_META + (size_t)NTOK * 4;
constexpr size_t OFF_S2      = OFF_S1 + (size_t)NTOK * 4;
constexpr size_t OFF_RAW     = OFF_S2 + (size_t)NTOK * 4;
constexpr size_t OFF_S       = OFF_RAW + (size_t)NTOK * 8 * 4;
constexpr size_t OFF_C       = OFF_S + 64 * 4;
constexpr size_t OFF_ZP      = OFF_C + 64 * 4;          // 2 KiB zero page (1024 bf16)
constexpr size_t MISC_SZ     = 2 << 20;
static_assert(OFF_ZP + 2048 <= MISC_SZ, "misc overflow");

constexpr size_t SZ_W1T_E = (size_t)HIDc * DIMc * 2;    // 4 MiB
constexpr size_t SZ_W2T_E = (size_t)DIMc * HIDc * 2;    // 4 MiB
constexpr size_t SZ_HID_E = (size_t)SLOTPE * HIDc * 2;  // 16 MiB
constexpr size_t SZ_EO    = (size_t)NSLOT * DIMc * 2;   // 64 MiB
constexpr size_t SZ_XBF   = (size_t)NTOK * DIMc * 2;    // 32 MiB

// layout: eo | xbf | per-round {w1T, w2T, hid} | misc
__device__ __host__ inline size_t layout_need(int epr) {
    return SZ_EO + SZ_XBF + (size_t)epr * (SZ_W1T_E + SZ_W2T_E + SZ_HID_E) + MISC_SZ;
}

// ---------------- helpers ----------------
__device__ inline u16 f2bf(float f) {
    u32 u = __float_as_uint(f);
    u32 r = (u + 0x7fffu + ((u >> 16) & 1u)) >> 16;
    return (u16)r;
}
__device__ inline u32 pack2(float lo, float hi) {
    return (u32)f2bf(lo) | ((u32)f2bf(hi) << 16);
}
__device__ inline float bflo(u32 u) { return __uint_as_float(u << 16); }
__device__ inline float bfhi(u32 u) { return __uint_as_float(u & 0xffff0000u); }

// tanh-approx gelu via exp2 (max abs err ~1e-3)
__device__ inline float gelu_fast(float v) {
    const float u = v * (0.7978845608028654f + 0.0356774081363001f * v * v);
    return v / (1.f + __builtin_exp2f(-2.885390081777927f * u));
}

#define GLDS16(gp, lp)                                                          \
    __builtin_amdgcn_global_load_lds(                                          \
        (const __attribute__((address_space(1))) void*)(gp),                   \
        (__attribute__((address_space(3))) void*)(lp), 16, 0, 0)

// ---------------- gating: one wave per token; also emits xbf (bf16 x) ----------------
__global__ __launch_bounds__(256) void gate_kernel(
    const float* __restrict__ x, const float* __restrict__ wg,
    const float* __restrict__ rp, float* __restrict__ raw_out,
    float* __restrict__ g1_out, float* __restrict__ g2_out, int* __restrict__ meta_out,
    u16* __restrict__ xbf)
{
    const int tk   = blockIdx.x * 4 + (threadIdx.x >> 6);
    const int lane = threadIdx.x & 63;
    const float* xr = x + (size_t)tk * DIMc;
    u16* xb = xbf + (size_t)tk * DIMc;

    float acc[8] = {0.f, 0.f, 0.f, 0.f, 0.f, 0.f, 0.f, 0.f};
#pragma unroll
    for (int i = 0; i < 4; ++i) {
        const int d0 = i * 256 + lane * 4;
        float4 xv = *(const float4*)(xr + d0);
        uint2 pk;
        pk.x = pack2(xv.x, xv.y);
        pk.y = pack2(xv.z, xv.w);
        *(uint2*)(xb + d0) = pk;
#pragma unroll
        for (int j = 0; j < 4; ++j) {
            float xs = (&xv.x)[j];
            float4 w0 = *(const float4*)(wg + (size_t)(d0 + j) * 8);
            float4 w1 = *(const float4*)(wg + (size_t)(d0 + j) * 8 + 4);
            acc[0] += xs * w0.x; acc[1] += xs * w0.y; acc[2] += xs * w0.z; acc[3] += xs * w0.w;
            acc[4] += xs * w1.x; acc[5] += xs * w1.y; acc[6] += xs * w1.z; acc[7] += xs * w1.w;
        }
    }
#pragma unroll
    for (int e = 0; e < 8; ++e) {
#pragma unroll
        for (int off = 1; off < 64; off <<= 1) acc[e] += __shfl_xor(acc[e], off);
    }

    if (lane == 0) {
        float mx = acc[0];
#pragma unroll
        for (int e = 1; e < 8; ++e) mx = fmaxf(mx, acc[e]);
        float ex[8], s = 0.f;
#pragma unroll
        for (int e = 0; e < 8; ++e) { ex[e] = expf(acc[e] - mx); s += ex[e]; }
        float inv = 1.f / s;
        float raw[8];
#pragma unroll
        for (int e = 0; e < 8; ++e) raw[e] = ex[e] * inv;

        int i1 = 0; float g1 = raw[0];
#pragma unroll
        for (int e = 1; e < 8; ++e) if (raw[e] > g1) { g1 = raw[e]; i1 = e; }
        int i2 = -1; float g2 = -1.f;
#pragma unroll
        for (int e = 0; e < 8; ++e) if (e != i1 && raw[e] > g2) { g2 = raw[e]; i2 = e; }

        float denom = g1 + g2 + 1e-9f;
        float g1n = g1 / denom, g2n = g2 / denom;
        int keep = (rp[tk] < (g2n / 0.2f)) ? 1 : 0;

        float* ro = raw_out + (size_t)tk * 8;
#pragma unroll
        for (int e = 0; e < 8; ++e) ro[e] = raw[e];
        g1_out[tk] = g1n;
        g2_out[tk] = g2n;
        meta_out[tk] = i1 | (i2 << 4) | (keep << 8);
    }
}

// ---------------- per-batch capacity scan (also inits slot map + zero page) ----------------
__global__ __launch_bounds__(256) void scan_kernel(
    const int* __restrict__ meta, const float* __restrict__ g1, const float* __restrict__ g2,
    int* __restrict__ slot_token, int* __restrict__ slot1, int* __restrict__ slot2,
    u32* __restrict__ zp)
{
    const int b = blockIdx.x;
    const int t = threadIdx.x;
    __shared__ int cnt[256][8];
    __shared__ int base_e[8];

    // fold-in: init this block's slot slice (batch b, all experts) + zero page
#pragma unroll
    for (int j = 0; j < 16; ++j) {
        const int idx = t * 16 + j;                       // e*512 + pos
        slot_token[(((idx >> 9) * Bc + b) << 9) | (idx & 511)] = -1;
    }
    if (b == 0) { zp[t * 2] = 0u; zp[t * 2 + 1] = 0u; }   // 512 u32 = 1024 bf16

    int m[8];
#pragma unroll
    for (int i = 0; i < 8; ++i) m[i] = meta[b * Nc + t * 8 + i];

    int c[8] = {0, 0, 0, 0, 0, 0, 0, 0};
#pragma unroll
    for (int i = 0; i < 8; ++i) c[m[i] & 15]++;
#pragma unroll
    for (int e = 0; e < 8; ++e) cnt[t][e] = c[e];
    __syncthreads();
    if (t < 8) {
        int run = 0;
        for (int i = 0; i < 256; ++i) { int v = cnt[i][t]; cnt[i][t] = run; run += v; }
        base_e[t] = run < CAPc ? run : CAPc;
    }
    __syncthreads();
#pragma unroll
    for (int e = 0; e < 8; ++e) c[e] = cnt[t][e];
#pragma unroll
    for (int i = 0; i < 8; ++i) {
        const int tk = b * Nc + t * 8 + i;
        const int e = m[i] & 15;
        const int pos = c[e]++;
        if (pos < CAPc) {
            const int slot = ((e * Bc + b) << 9) | pos;
            slot_token[slot] = tk;
            slot1[tk] = slot;
        } else {
            slot1[tk] = -1;
        }
    }
    __syncthreads();

#pragma unroll
    for (int e = 0; e < 8; ++e) c[e] = 0;
#pragma unroll
    for (int i = 0; i < 8; ++i) {
        if ((m[i] >> 8) & 1) c[(m[i] >> 4) & 15]++;
    }
#pragma unroll
    for (int e = 0; e < 8; ++e) cnt[t][e] = c[e];
    __syncthreads();
    if (t < 8) {
        int run = 0;
        for (int i = 0; i < 256; ++i) { int v = cnt[i][t]; cnt[i][t] = run; run += v; }
    }
    __syncthreads();
#pragma unroll
    for (int e = 0; e < 8; ++e) c[e] = cnt[t][e];
#pragma unroll
    for (int i = 0; i < 8; ++i) {
        const int tk = b * Nc + t * 8 + i;
        int s2v = -1;
        if ((m[i] >> 8) & 1) {
            const int e = (m[i] >> 4) & 15;
            const int pos = base_e[e] + c[e]++;
            if (pos < CAPc) {
                const int slot = ((e * Bc + b) << 9) | pos;
                slot_token[slot] = tk;
                s2v = slot;
            }
        }
        slot2[tk] = s2v;
    }
}

// ---------------- loss reduction ----------------
__global__ __launch_bounds__(256) void reduce_stats_kernel(
    const float* __restrict__ raw, const int* __restrict__ meta,
    float* __restrict__ S, float* __restrict__ C)
{
    const int be = blockIdx.x, b = be >> 3, e = be & 7;
    float s = 0.f, c = 0.f;
    for (int n = threadIdx.x; n < Nc; n += 256) {
        const int tk = b * Nc + n;
        s += raw[(size_t)tk * 8 + e];
        c += ((meta[tk] & 15) == e) ? 1.f : 0.f;
    }
    __shared__ float sh_s[4], sh_c[4];
    const int lane = threadIdx.x & 63, wv = threadIdx.x >> 6;
#pragma unroll
    for (int off = 32; off; off >>= 1) { s += __shfl_down(s, off); c += __shfl_down(c, off); }
    if (lane == 0) { sh_s[wv] = s; sh_c[wv] = c; }
    __syncthreads();
    if (threadIdx.x == 0) {
        S[be] = sh_s[0] + sh_s[1] + sh_s[2] + sh_s[3];
        C[be] = sh_c[0] + sh_c[1] + sh_c[2] + sh_c[3];
    }
}

__global__ void loss_kernel(const float* __restrict__ S, const float* __restrict__ C,
                            float* __restrict__ dst)
{
    float v = S[threadIdx.x] * C[threadIdx.x];
#pragma unroll
    for (int off = 32; off; off >>= 1) v += __shfl_down(v, off);
    if (threadIdx.x == 0) *dst = v * (0.01f / ((float)Nc * (float)Nc));
}

// ---------------- weight transpose + bf16 convert ----------------
template <int R, int C>
__global__ __launch_bounds__(256) void transpose_kernel(
    const float* __restrict__ w, u16* __restrict__ wT, const int e0)
{
    __shared__ float tile[32][33];
    const int ez = blockIdx.z;
    const int c0 = blockIdx.x * 32, r0 = blockIdx.y * 32;
    const float* src = w + (size_t)(e0 + ez) * R * C;
    u16* dst = wT + (size_t)ez * C * R;
    const int t = threadIdx.x;
#pragma unroll
    for (int i = 0; i < 4; ++i) {
        const int r = i * 8 + (t >> 5), cc = t & 31;
        tile[r][cc] = src[(size_t)(r0 + r) * C + c0 + cc];
    }
    __syncthreads();
#pragma unroll
    for (int i = 0; i < 4; ++i) {
        const int cc = i * 8 + (t >> 5), r = t & 31;
        dst[(size_t)(c0 + cc) * R + r0 + r] = f2bf(tile[r][cc]);
    }
}

// ---------------- tile swizzle helper (XCD chunk + GN=4 n-grouping) ----------------
__device__ inline void tile_swizzle(int& mt, int& nt) {
    const int MT = gridDim.x;
    const int lin = blockIdx.y * MT + blockIdx.x;
    const int nb  = MT * gridDim.y;
    const int per = nb >> 3;
    const int sid = (lin & 7) * per + (lin >> 3);
    const int gsz = MT << 2;
    const int g   = sid / gsz;
    const int r   = sid - g * gsz;
    mt = r >> 2;
    nt = (g << 2) + (r & 3);
}

// ---------------- gemm1: A = xbf rows via slot_token indirection (gather fused) ----------------
// 128x128 BK=64, 4 waves, single-buffered 32 KiB LDS, slot-XOR LDS swizzle
// (round-11-verified, 0 conflicts). Empty slots -> 2 KiB zero page.
__global__ __launch_bounds__(256, 4) void gemm1_kernel(
    const u16* __restrict__ xbf, const int* __restrict__ slot_tok_round,
    const u16* __restrict__ Bt, u16* __restrict__ Cc, const u16* __restrict__ zp)
{
    constexpr int K = DIMc;
    __shared__ u16 As[128 * 64];
    __shared__ u16 Bs[128 * 64];

    const int tid = threadIdx.x;
    const int wv = tid >> 6, lane = tid & 63;

    int mt, nt;
    tile_swizzle(mt, nt);
    const int m0 = mt * 128, n0 = nt * 128;
    const int e = mt >> 5;

    const int wr = wv >> 1, wc = wv & 1;
    const int lr = lane & 15, lk = lane >> 4;

    const int rb = tid >> 3;
    const int gc = (((tid & 7) ^ ((tid >> 3) & 7)) * 8);

    // per-row token indirection (resolved once)
    const u16* pa[4];
#pragma unroll
    for (int p = 0; p < 4; ++p) {
        const int tk = slot_tok_round[m0 + rb + 32 * p];
        pa[p] = ((tk >= 0) ? xbf + ((size_t)tk << 10) : zp) + gc;
    }
    const u16* pbb = Bt + ((size_t)e * HIDc + n0 + rb) * K + gc;
    const u16* pb1 = pbb + (size_t)32 * K;
    const u16* pb2 = pbb + (size_t)64 * K;
    const u16* pb3 = pbb + (size_t)96 * K;

    u16* la = As + tid * 8;
    u16* lb = Bs + tid * 8;

    f32x4 acc[4][4];
#pragma unroll
    for (int i = 0; i < 4; ++i)
#pragma unroll
        for (int j = 0; j < 4; ++j) acc[i][j] = (f32x4)0.f;

    for (int k0 = 0; k0 < K; k0 += 64) {
        __syncthreads();
        GLDS16(pa[0], la);        GLDS16(pa[1], la + 2048);
        GLDS16(pa[2], la + 4096); GLDS16(pa[3], la + 6144);
        GLDS16(pbb, lb);          GLDS16(pb1, lb + 2048);
        GLDS16(pb2, lb + 4096);   GLDS16(pb3, lb + 6144);
#pragma unroll
        for (int p = 0; p < 4; ++p) pa[p] += 64;
        pbb += 64; pb1 += 64; pb2 += 64; pb3 += 64;
        __syncthreads();

#pragma unroll
        for (int kk = 0; kk < 2; ++kk) {
            const int sl = ((kk * 4 + lk) ^ (lr & 7)) * 8;
            short8 a[4], b[4];
#pragma unroll
            for (int f = 0; f < 4; ++f) {
                a[f] = *(const short8*)(As + (wr * 64 + f * 16 + lr) * 64 + sl);
                b[f] = *(const short8*)(Bs + (wc * 64 + f * 16 + lr) * 64 + sl);
            }
#pragma unroll
            for (int fm = 0; fm < 4; ++fm)
#pragma unroll
                for (int fn = 0; fn < 4; ++fn)
                    acc[fm][fn] = __builtin_amdgcn_mfma_f32_16x16x32_bf16(
                        a[fm], b[fn], acc[fm][fn], 0, 0, 0);
        }
    }

#pragma unroll
    for (int fm = 0; fm < 4; ++fm) {
        const int row = m0 + wr * 64 + fm * 16 + lk * 4;
#pragma unroll
        for (int fn = 0; fn < 4; ++fn) {
            const int col = n0 + wc * 64 + fn * 16 + lr;
#pragma unroll
            for (int r2 = 0; r2 < 4; ++r2) {
                Cc[(size_t)(row + r2) * HIDc + col] = f2bf(gelu_fast(acc[fm][fn][r2]));
            }
        }
    }
}

// ---------------- gemm2: round-11 body verbatim (plain bf16 store) ----------------
__global__ __launch_bounds__(256, 4) void gemm2_kernel(
    const u16* __restrict__ A, const u16* __restrict__ Bt, u16* __restrict__ Cc)
{
    constexpr int K = HIDc;
    __shared__ u16 As[128 * 64];
    __shared__ u16 Bs[128 * 64];

    const int tid = threadIdx.x;
    const int wv = tid >> 6, lane = tid & 63;

    int mt, nt;
    tile_swizzle(mt, nt);
    const int m0 = mt * 128, n0 = nt * 128;
    const int e = mt >> 5;

    const int wr = wv >> 1, wc = wv & 1;
    const int lr = lane & 15, lk = lane >> 4;

    const int rb = tid >> 3;
    const int gc = (((tid & 7) ^ ((tid >> 3) & 7)) * 8);

    const u16* pa0 = A + (size_t)(m0 + rb) * K + gc;
    const u16* pa1 = pa0 + (size_t)32 * K;
    const u16* pa2 = pa0 + (size_t)64 * K;
    const u16* pa3 = pa0 + (size_t)96 * K;
    const u16* pbb = Bt + ((size_t)e * DIMc + n0 + rb) * K + gc;
    const u16* pb1 = pbb + (size_t)32 * K;
    const u16* pb2 = pbb + (size_t)64 * K;
    const u16* pb3 = pbb + (size_t)96 * K;

    u16* la = As + tid * 8;
    u16* lb = Bs + tid * 8;

    f32x4 acc[4][4];
#pragma unroll
    for (int i = 0; i < 4; ++i)
#pragma unroll
        for (int j = 0; j < 4; ++j) acc[i][j] = (f32x4)0.f;

    for (int k0 = 0; k0 < K; k0 += 64) {
        __syncthreads();
        GLDS16(pa0, la);        GLDS16(pa1, la + 2048);
        GLDS16(pa2, la + 4096); GLDS16(pa3, la + 6144);
        GLDS16(pbb, lb);        GLDS16(pb1, lb + 2048);
        GLDS16(pb2, lb + 4096); GLDS16(pb3, lb + 6144);
        pa0 += 64; pa1 += 64; pa2 += 64; pa3 += 64;
        pbb += 64; pb1 += 64; pb2 += 64; pb3 += 64;
        __syncthreads();

#pragma unroll
        for (int kk = 0; kk < 2; ++kk) {
            const int sl = ((kk * 4 + lk) ^ (lr & 7)) * 8;
            short8 a[4], b[4];
#pragma unroll
            for (int f = 0; f < 4; ++f) {
                a[f] = *(const short8*)(As + (wr * 64 + f * 16 + lr) * 64 + sl);
                b[f] = *(const short8*)(Bs + (wc * 64 + f * 16 + lr) * 64 + sl);
            }
#pragma unroll
            for (int fm = 0; fm < 4; ++fm)
#pragma unroll
                for (int fn = 0; fn < 4; ++fn)
                    acc[fm][fn] = __builtin_amdgcn_mfma_f32_16x16x32_bf16(
                        a[fm], b[fn], acc[fm][fn], 0, 0, 0);
        }
    }

#pragma unroll
    for (int fm = 0; fm < 4; ++fm) {
        const int row = m0 + wr * 64 + fm * 16 + lk * 4;
#pragma unroll
        for (int fn = 0; fn < 4; ++fn) {
            const int col = n0 + wc * 64 + fn * 16 + lr;
#pragma unroll
            for (int r2 = 0; r2 < 4; ++r2) {
                Cc[(size_t)(row + r2) * DIMc + col] = f2bf(acc[fm][fn][r2]);
            }
        }
    }
}

// ---------------- combine: out[tk] = g1*eo[s1] + g2*eo[s2] (fully coalesced) ----------------
__global__ __launch_bounds__(256) void combine_kernel(
    const u16* __restrict__ eo, const int* __restrict__ slot1, const int* __restrict__ slot2,
    const float* __restrict__ g1, const float* __restrict__ g2, float* __restrict__ out)
{
    const int tk = blockIdx.x * 4 + (threadIdx.x >> 6);
    const int lane = threadIdx.x & 63;
    int s1 = slot1[tk], s2 = slot2[tk];
    const float a = (s1 >= 0) ? g1[tk] : 0.f;
    const float b = (s2 >= 0) ? g2[tk] : 0.f;
    if (s1 < 0) s1 = 0;
    if (s2 < 0) s2 = 0;
    const uint4* p1 = (const uint4*)(eo + ((size_t)s1 << 10)) + lane * 2;
    const uint4* p2 = (const uint4*)(eo + ((size_t)s2 << 10)) + lane * 2;
    uint4 x0 = p1[0], x1 = p1[1];
    uint4 y0 = p2[0], y1 = p2[1];
    float4* dst = (float4*)(out + ((size_t)tk << 10)) + lane * 4;
    float4 o;
    o.x = a * bflo(x0.x) + b * bflo(y0.x); o.y = a * bfhi(x0.x) + b * bfhi(y0.x);
    o.z = a * bflo(x0.y) + b * bflo(y0.y); o.w = a * bfhi(x0.y) + b * bfhi(y0.y);
    dst[0] = o;
    o.x = a * bflo(x0.z) + b * bflo(y0.z); o.y = a * bfhi(x0.z) + b * bfhi(y0.z);
    o.z = a * bflo(x0.w) + b * bflo(y0.w); o.w = a * bfhi(x0.w) + b * bfhi(y0.w);
    dst[1] = o;
    o.x = a * bflo(x1.x) + b * bflo(y1.x); o.y = a * bfhi(x1.x) + b * bfhi(y1.x);
    o.z = a * bflo(x1.y) + b * bflo(y1.y); o.w = a * bfhi(x1.y) + b * bfhi(y1.y);
    dst[2] = o;
    o.x = a * bflo(x1.z) + b * bflo(y1.z); o.y = a * bfhi(x1.z) + b * bfhi(y1.z);
    o.z = a * bflo(x1.w) + b * bflo(y1.w); o.w = a * bfhi(x1.w) + b * bfhi(y1.w);
    dst[3] = o;
}

// ---------------- launch ----------------
extern "C" void kernel_launch(void* const* d_in, const int* in_sizes, int n_in,
                              void* d_out, int out_size, void* d_ws, size_t ws_size,
                              hipStream_t stream)
{
    (void)in_sizes; (void)n_in; (void)out_size;

    const float* x  = (const float*)d_in[0];
    const float* wg = (const float*)d_in[1];
    const float* w1 = (const float*)d_in[2];
    const float* w2 = (const float*)d_in[3];
    const float* rp = (const float*)d_in[4];
    float* out = (float*)d_out;
    char* ws = (char*)d_ws;

    int epr = 4;
    while (epr > 1 && layout_need(epr) > ws_size) epr >>= 1;
    if (layout_need(epr) > ws_size) return;

    u16* eo  = (u16*)(ws);
    u16* xbf = (u16*)(ws + SZ_EO);
    u16* w1T = (u16*)(ws + SZ_EO + SZ_XBF);
    u16* w2T = (u16*)(ws + SZ_EO + SZ_XBF + (size_t)epr * SZ_W1T_E);
    u16* hid = (u16*)(ws + SZ_EO + SZ_XBF + (size_t)epr * (SZ_W1T_E + SZ_W2T_E));
    char* misc = ws + SZ_EO + SZ_XBF + (size_t)epr * (SZ_W1T_E + SZ_W2T_E + SZ_HID_E);

    int* slot_token = (int*)(misc + OFF_SLOTTOK);
    float* g1 = (float*)(misc + OFF_G1);
    float* g2 = (float*)(misc + OFF_G2);
    int* meta = (int*)(misc + OFF_META);
    int* s1 = (int*)(misc + OFF_S1);
    int* s2 = (int*)(misc + OFF_S2);
    float* raw = (float*)(misc + OFF_RAW);
    float* Sr = (float*)(misc + OFF_S);
    float* C1 = (float*)(misc + OFF_C);
    u16* zp = (u16*)(misc + OFF_ZP);

    gate_kernel<<<NTOK / 4, 256, 0, stream>>>(x, wg, rp, raw, g1, g2, meta, xbf);
    scan_kernel<<<Bc, 256, 0, stream>>>(meta, g1, g2, slot_token, s1, s2, (u32*)zp);
    reduce_stats_kernel<<<64, 256, 0, stream>>>(raw, meta, Sr, C1);
    loss_kernel<<<1, 64, 0, stream>>>(Sr, C1, out + (size_t)NTOK * DIMc);

    for (int e0 = 0; e0 < Ec; e0 += epr) {
        transpose_kernel<DIMc, HIDc><<<dim3(HIDc / 32, DIMc / 32, epr), 256, 0, stream>>>(
            w1, w1T, e0);
        transpose_kernel<HIDc, DIMc><<<dim3(DIMc / 32, HIDc / 32, epr), 256, 0, stream>>>(
            w2, w2T, e0);

        gemm1_kernel<<<dim3(epr * 32, HIDc / 128), 256, 0, stream>>>(
            xbf, slot_token + e0 * SLOTPE, w1T, hid, zp);
        gemm2_kernel<<<dim3(epr * 32, DIMc / 128), 256, 0, stream>>>(
            hid, w2T, eo + (size_t)e0 * SLOTPE * DIMc);
    }

    combine_kernel<<<NTOK / 4, 256, 0, stream>>>(eo, s1, s2, g1, g2, out);
}

// Round 14
// 422.077 us; speedup vs baseline: 1.1172x; 1.0184x over previous
//
#include <hip/hip_runtime.h>
#include <hip/hip_bf16.h>

typedef unsigned short u16;
typedef unsigned int u32;

typedef short short8 __attribute__((ext_vector_type(8)));
typedef float f32x4 __attribute__((ext_vector_type(4)));

// ---------------- problem constants ----------------
constexpr int Bc   = 8;
constexpr int Nc   = 2048;
constexpr int DIMc = 1024;
constexpr int Ec   = 8;
constexpr int HIDc = 2048;
constexpr int CAPc = 512;
constexpr int NTOK   = Bc * Nc;        // 16384
constexpr int SLOTPE = Bc * CAPc;      // 4096 slots per expert
constexpr int NSLOT  = Ec * SLOTPE;    // 32768

// ---------------- misc block layout (relative offsets, 2 MiB) ----------------
constexpr size_t OFF_SLOTTOK = 0;
constexpr size_t OFF_G1      = OFF_SLOTTOK + (size_t)NSLOT * 4;
constexpr size_t OFF_G2      = OFF_G1 + (size_t)NTOK * 4;
constexpr size_t OFF_META    = OFF_G2 + (size_t)NTOK * 4;
constexpr size_t OFF_S1      = OFF_META + (size_t)NTOK * 4;
constexpr size_t OFF_S2      = OFF_S1 + (size_t)NTOK * 4;
constexpr size_t OFF_RAW     = OFF_S2 + (size_t)NTOK * 4;
constexpr size_t OFF_S       = OFF_RAW + (size_t)NTOK * 8 * 4;
constexpr size_t OFF_C       = OFF_S + 64 * 4;
constexpr size_t OFF_ZP      = OFF_C + 64 * 4;          // 2 KiB zero page (1024 bf16)
constexpr size_t MISC_SZ     = 2 << 20;
static_assert(OFF_ZP + 2048 <= MISC_SZ, "misc overflow");

constexpr size_t SZ_W1T_E = (size_t)HIDc * DIMc * 2;    // 4 MiB
constexpr size_t SZ_W2T_E = (size_t)DIMc * HIDc * 2;    // 4 MiB
constexpr size_t SZ_HID_E = (size_t)SLOTPE * HIDc * 2;  // 16 MiB
constexpr size_t SZ_EO    = (size_t)NSLOT * DIMc * 2;   // 64 MiB
constexpr size_t SZ_XBF   = (size_t)NTOK * DIMc * 2;    // 32 MiB

// layout: eo | xbf | per-round {w1T, w2T, hid} | misc
__device__ __host__ inline size_t layout_need(int epr) {
    return SZ_EO + SZ_XBF + (size_t)epr * (SZ_W1T_E + SZ_W2T_E + SZ_HID_E) + MISC_SZ;
}

// ---------------- helpers ----------------
__device__ inline u16 f2bf(float f) {
    u32 u = __float_as_uint(f);
    u32 r = (u + 0x7fffu + ((u >> 16) & 1u)) >> 16;
    return (u16)r;
}
__device__ inline u32 pack2(float lo, float hi) {
    return (u32)f2bf(lo) | ((u32)f2bf(hi) << 16);
}
__device__ inline float bflo(u32 u) { return __uint_as_float(u << 16); }
__device__ inline float bfhi(u32 u) { return __uint_as_float(u & 0xffff0000u); }

// tanh-approx gelu via exp2 (max abs err ~1e-3)
__device__ inline float gelu_fast(float v) {
    const float u = v * (0.7978845608028654f + 0.0356774081363001f * v * v);
    return v / (1.f + __builtin_exp2f(-2.885390081777927f * u));
}

#define GLDS16(gp, lp)                                                          \
    __builtin_amdgcn_global_load_lds(                                          \
        (const __attribute__((address_space(1))) void*)(gp),                   \
        (__attribute__((address_space(3))) void*)(lp), 16, 0, 0)

// ---------------- gating: one wave per token; also emits xbf (bf16 x) ----------------
__global__ __launch_bounds__(256) void gate_kernel(
    const float* __restrict__ x, const float* __restrict__ wg,
    const float* __restrict__ rp, float* __restrict__ raw_out,
    float* __restrict__ g1_out, float* __restrict__ g2_out, int* __restrict__ meta_out,
    u16* __restrict__ xbf)
{
    const int tk   = blockIdx.x * 4 + (threadIdx.x >> 6);
    const int lane = threadIdx.x & 63;
    const float* xr = x + (size_t)tk * DIMc;
    u16* xb = xbf + (size_t)tk * DIMc;

    float acc[8] = {0.f, 0.f, 0.f, 0.f, 0.f, 0.f, 0.f, 0.f};
#pragma unroll
    for (int i = 0; i < 4; ++i) {
        const int d0 = i * 256 + lane * 4;
        float4 xv = *(const float4*)(xr + d0);
        uint2 pk;
        pk.x = pack2(xv.x, xv.y);
        pk.y = pack2(xv.z, xv.w);
        *(uint2*)(xb + d0) = pk;
#pragma unroll
        for (int j = 0; j < 4; ++j) {
            float xs = (&xv.x)[j];
            float4 w0 = *(const float4*)(wg + (size_t)(d0 + j) * 8);
            float4 w1 = *(const float4*)(wg + (size_t)(d0 + j) * 8 + 4);
            acc[0] += xs * w0.x; acc[1] += xs * w0.y; acc[2] += xs * w0.z; acc[3] += xs * w0.w;
            acc[4] += xs * w1.x; acc[5] += xs * w1.y; acc[6] += xs * w1.z; acc[7] += xs * w1.w;
        }
    }
#pragma unroll
    for (int e = 0; e < 8; ++e) {
#pragma unroll
        for (int off = 1; off < 64; off <<= 1) acc[e] += __shfl_xor(acc[e], off);
    }

    if (lane == 0) {
        float mx = acc[0];
#pragma unroll
        for (int e = 1; e < 8; ++e) mx = fmaxf(mx, acc[e]);
        float ex[8], s = 0.f;
#pragma unroll
        for (int e = 0; e < 8; ++e) { ex[e] = expf(acc[e] - mx); s += ex[e]; }
        float inv = 1.f / s;
        float raw[8];
#pragma unroll
        for (int e = 0; e < 8; ++e) raw[e] = ex[e] * inv;

        int i1 = 0; float g1 = raw[0];
#pragma unroll
        for (int e = 1; e < 8; ++e) if (raw[e] > g1) { g1 = raw[e]; i1 = e; }
        int i2 = -1; float g2 = -1.f;
#pragma unroll
        for (int e = 0; e < 8; ++e) if (e != i1 && raw[e] > g2) { g2 = raw[e]; i2 = e; }

        float denom = g1 + g2 + 1e-9f;
        float g1n = g1 / denom, g2n = g2 / denom;
        int keep = (rp[tk] < (g2n / 0.2f)) ? 1 : 0;

        float* ro = raw_out + (size_t)tk * 8;
#pragma unroll
        for (int e = 0; e < 8; ++e) ro[e] = raw[e];
        g1_out[tk] = g1n;
        g2_out[tk] = g2n;
        meta_out[tk] = i1 | (i2 << 4) | (keep << 8);
    }
}

// ---------------- per-batch capacity scan + fused loss stats ----------------
// Also inits slot map slice + zero page.  S[b*8+e] = sum_n raw[b,n,e];
// C[b*8+e] = count(argmax==e) (uncapped) — exactly density_1*Nc.
__global__ __launch_bounds__(256) void scan_kernel(
    const int* __restrict__ meta, const float* __restrict__ g1, const float* __restrict__ g2,
    const float* __restrict__ raw,
    int* __restrict__ slot_token, int* __restrict__ slot1, int* __restrict__ slot2,
    float* __restrict__ S, float* __restrict__ Cc, u32* __restrict__ zp)
{
    const int b = blockIdx.x;
    const int t = threadIdx.x;
    __shared__ int cnt[256][8];
    __shared__ float psum[256][8];
    __shared__ int base_e[8];

    // fold-in: init this block's slot slice (batch b, all experts) + zero page
#pragma unroll
    for (int j = 0; j < 16; ++j) {
        const int idx = t * 16 + j;                       // e*512 + pos
        slot_token[(((idx >> 9) * Bc + b) << 9) | (idx & 511)] = -1;
    }
    if (b == 0) { zp[t * 2] = 0u; zp[t * 2 + 1] = 0u; }   // 512 u32 = 1024 bf16

    int m[8];
#pragma unroll
    for (int i = 0; i < 8; ++i) m[i] = meta[b * Nc + t * 8 + i];

    // raw sums for this thread's 8 tokens (contiguous 64 floats -> coalesced)
    {
        float rs[8] = {0.f, 0.f, 0.f, 0.f, 0.f, 0.f, 0.f, 0.f};
        const float* rbase = raw + ((size_t)(b * Nc + t * 8)) * 8;
#pragma unroll
        for (int i = 0; i < 8; ++i) {
            float4 lo = *(const float4*)(rbase + i * 8);
            float4 hi = *(const float4*)(rbase + i * 8 + 4);
            rs[0] += lo.x; rs[1] += lo.y; rs[2] += lo.z; rs[3] += lo.w;
            rs[4] += hi.x; rs[5] += hi.y; rs[6] += hi.z; rs[7] += hi.w;
        }
#pragma unroll
        for (int e = 0; e < 8; ++e) psum[t][e] = rs[e];
    }

    int c[8] = {0, 0, 0, 0, 0, 0, 0, 0};
#pragma unroll
    for (int i = 0; i < 8; ++i) c[m[i] & 15]++;
#pragma unroll
    for (int e = 0; e < 8; ++e) cnt[t][e] = c[e];
    __syncthreads();
    if (t < 8) {
        int run = 0;
        float s = 0.f;
        for (int i = 0; i < 256; ++i) {
            int v = cnt[i][t]; cnt[i][t] = run; run += v;
            s += psum[i][t];
        }
        base_e[t] = run < CAPc ? run : CAPc;
        Cc[b * 8 + t] = (float)run;     // uncapped count = density_1 * Nc
        S[b * 8 + t]  = s;
    }
    __syncthreads();
#pragma unroll
    for (int e = 0; e < 8; ++e) c[e] = cnt[t][e];
#pragma unroll
    for (int i = 0; i < 8; ++i) {
        const int tk = b * Nc + t * 8 + i;
        const int e = m[i] & 15;
        const int pos = c[e]++;
        if (pos < CAPc) {
            const int slot = ((e * Bc + b) << 9) | pos;
            slot_token[slot] = tk;
            slot1[tk] = slot;
        } else {
            slot1[tk] = -1;
        }
    }
    __syncthreads();

#pragma unroll
    for (int e = 0; e < 8; ++e) c[e] = 0;
#pragma unroll
    for (int i = 0; i < 8; ++i) {
        if ((m[i] >> 8) & 1) c[(m[i] >> 4) & 15]++;
    }
#pragma unroll
    for (int e = 0; e < 8; ++e) cnt[t][e] = c[e];
    __syncthreads();
    if (t < 8) {
        int run = 0;
        for (int i = 0; i < 256; ++i) { int v = cnt[i][t]; cnt[i][t] = run; run += v; }
    }
    __syncthreads();
#pragma unroll
    for (int e = 0; e < 8; ++e) c[e] = cnt[t][e];
#pragma unroll
    for (int i = 0; i < 8; ++i) {
        const int tk = b * Nc + t * 8 + i;
        int s2v = -1;
        if ((m[i] >> 8) & 1) {
            const int e = (m[i] >> 4) & 15;
            const int pos = base_e[e] + c[e]++;
            if (pos < CAPc) {
                const int slot = ((e * Bc + b) << 9) | pos;
                slot_token[slot] = tk;
                s2v = slot;
            }
        }
        slot2[tk] = s2v;
    }
}

// ---------------- merged weight transpose + bf16 convert (w1 & w2 in one launch) ----------------
// blockIdx.y = z: z < epr -> w1 expert z (R=DIM, C=HID); else w2 expert z-epr (R=HID, C=DIM).
// 2048 32x32 tiles per matrix in both cases.
__global__ __launch_bounds__(256) void transpose_all_kernel(
    const float* __restrict__ w1, const float* __restrict__ w2,
    u16* __restrict__ w1T, u16* __restrict__ w2T, const int e0, const int epr)
{
    __shared__ float tile[32][33];
    const int z = blockIdx.y;
    const bool is1 = z < epr;
    const int ez = is1 ? z : z - epr;
    const int R = is1 ? DIMc : HIDc;
    const int C = is1 ? HIDc : DIMc;
    const int xmask = (C / 32) - 1;
    const int xshift = is1 ? 6 : 5;
    const int blk = blockIdx.x;
    const int c0 = (blk & xmask) * 32, r0 = (blk >> xshift) * 32;
    const float* src = (is1 ? w1 : w2) + (size_t)(e0 + ez) * R * C;
    u16* dst = (is1 ? w1T : w2T) + (size_t)ez * C * R;
    const int t = threadIdx.x;
#pragma unroll
    for (int i = 0; i < 4; ++i) {
        const int r = i * 8 + (t >> 5), cc = t & 31;
        tile[r][cc] = src[(size_t)(r0 + r) * C + c0 + cc];
    }
    __syncthreads();
#pragma unroll
    for (int i = 0; i < 4; ++i) {
        const int cc = i * 8 + (t >> 5), r = t & 31;
        dst[(size_t)(c0 + cc) * R + r0 + r] = f2bf(tile[r][cc]);
    }
}

// ---------------- tile swizzle helper (XCD chunk + GN=4 n-grouping) ----------------
__device__ inline void tile_swizzle(int& mt, int& nt) {
    const int MT = gridDim.x;
    const int lin = blockIdx.y * MT + blockIdx.x;
    const int nb  = MT * gridDim.y;
    const int per = nb >> 3;
    const int sid = (lin & 7) * per + (lin >> 3);
    const int gsz = MT << 2;
    const int g   = sid / gsz;
    const int r   = sid - g * gsz;
    mt = r >> 2;
    nt = (g << 2) + (r & 3);
}

// ---------------- gemm1: A = xbf rows via slot_token indirection (gather fused) ----------------
__global__ __launch_bounds__(256, 4) void gemm1_kernel(
    const u16* __restrict__ xbf, const int* __restrict__ slot_tok_round,
    const u16* __restrict__ Bt, u16* __restrict__ Cc, const u16* __restrict__ zp)
{
    constexpr int K = DIMc;
    __shared__ u16 As[128 * 64];
    __shared__ u16 Bs[128 * 64];

    const int tid = threadIdx.x;
    const int wv = tid >> 6, lane = tid & 63;

    int mt, nt;
    tile_swizzle(mt, nt);
    const int m0 = mt * 128, n0 = nt * 128;
    const int e = mt >> 5;

    const int wr = wv >> 1, wc = wv & 1;
    const int lr = lane & 15, lk = lane >> 4;

    const int rb = tid >> 3;
    const int gc = (((tid & 7) ^ ((tid >> 3) & 7)) * 8);

    const u16* pa[4];
#pragma unroll
    for (int p = 0; p < 4; ++p) {
        const int tk = slot_tok_round[m0 + rb + 32 * p];
        pa[p] = ((tk >= 0) ? xbf + ((size_t)tk << 10) : zp) + gc;
    }
    const u16* pbb = Bt + ((size_t)e * HIDc + n0 + rb) * K + gc;
    const u16* pb1 = pbb + (size_t)32 * K;
    const u16* pb2 = pbb + (size_t)64 * K;
    const u16* pb3 = pbb + (size_t)96 * K;

    u16* la = As + tid * 8;
    u16* lb = Bs + tid * 8;

    f32x4 acc[4][4];
#pragma unroll
    for (int i = 0; i < 4; ++i)
#pragma unroll
        for (int j = 0; j < 4; ++j) acc[i][j] = (f32x4)0.f;

    for (int k0 = 0; k0 < K; k0 += 64) {
        __syncthreads();
        GLDS16(pa[0], la);        GLDS16(pa[1], la + 2048);
        GLDS16(pa[2], la + 4096); GLDS16(pa[3], la + 6144);
        GLDS16(pbb, lb);          GLDS16(pb1, lb + 2048);
        GLDS16(pb2, lb + 4096);   GLDS16(pb3, lb + 6144);
#pragma unroll
        for (int p = 0; p < 4; ++p) pa[p] += 64;
        pbb += 64; pb1 += 64; pb2 += 64; pb3 += 64;
        __syncthreads();

#pragma unroll
        for (int kk = 0; kk < 2; ++kk) {
            const int sl = ((kk * 4 + lk) ^ (lr & 7)) * 8;
            short8 a[4], b[4];
#pragma unroll
            for (int f = 0; f < 4; ++f) {
                a[f] = *(const short8*)(As + (wr * 64 + f * 16 + lr) * 64 + sl);
                b[f] = *(const short8*)(Bs + (wc * 64 + f * 16 + lr) * 64 + sl);
            }
#pragma unroll
            for (int fm = 0; fm < 4; ++fm)
#pragma unroll
                for (int fn = 0; fn < 4; ++fn)
                    acc[fm][fn] = __builtin_amdgcn_mfma_f32_16x16x32_bf16(
                        a[fm], b[fn], acc[fm][fn], 0, 0, 0);
        }
    }

#pragma unroll
    for (int fm = 0; fm < 4; ++fm) {
        const int row = m0 + wr * 64 + fm * 16 + lk * 4;
#pragma unroll
        for (int fn = 0; fn < 4; ++fn) {
            const int col = n0 + wc * 64 + fn * 16 + lr;
#pragma unroll
            for (int r2 = 0; r2 < 4; ++r2) {
                Cc[(size_t)(row + r2) * HIDc + col] = f2bf(gelu_fast(acc[fm][fn][r2]));
            }
        }
    }
}

// ---------------- gemm2: round-11 body verbatim (plain bf16 store) ----------------
__global__ __launch_bounds__(256, 4) void gemm2_kernel(
    const u16* __restrict__ A, const u16* __restrict__ Bt, u16* __restrict__ Cc)
{
    constexpr int K = HIDc;
    __shared__ u16 As[128 * 64];
    __shared__ u16 Bs[128 * 64];

    const int tid = threadIdx.x;
    const int wv = tid >> 6, lane = tid & 63;

    int mt, nt;
    tile_swizzle(mt, nt);
    const int m0 = mt * 128, n0 = nt * 128;
    const int e = mt >> 5;

    const int wr = wv >> 1, wc = wv & 1;
    const int lr = lane & 15, lk = lane >> 4;

    const int rb = tid >> 3;
    const int gc = (((tid & 7) ^ ((tid >> 3) & 7)) * 8);

    const u16* pa0 = A + (size_t)(m0 + rb) * K + gc;
    const u16* pa1 = pa0 + (size_t)32 * K;
    const u16* pa2 = pa0 + (size_t)64 * K;
    const u16* pa3 = pa0 + (size_t)96 * K;
    const u16* pbb = Bt + ((size_t)e * DIMc + n0 + rb) * K + gc;
    const u16* pb1 = pbb + (size_t)32 * K;
    const u16* pb2 = pbb + (size_t)64 * K;
    const u16* pb3 = pbb + (size_t)96 * K;

    u16* la = As + tid * 8;
    u16* lb = Bs + tid * 8;

    f32x4 acc[4][4];
#pragma unroll
    for (int i = 0; i < 4; ++i)
#pragma unroll
        for (int j = 0; j < 4; ++j) acc[i][j] = (f32x4)0.f;

    for (int k0 = 0; k0 < K; k0 += 64) {
        __syncthreads();
        GLDS16(pa0, la);        GLDS16(pa1, la + 2048);
        GLDS16(pa2, la + 4096); GLDS16(pa3, la + 6144);
        GLDS16(pbb, lb);        GLDS16(pb1, lb + 2048);
        GLDS16(pb2, lb + 4096); GLDS16(pb3, lb + 6144);
        pa0 += 64; pa1 += 64; pa2 += 64; pa3 += 64;
        pbb += 64; pb1 += 64; pb2 += 64; pb3 += 64;
        __syncthreads();

#pragma unroll
        for (int kk = 0; kk < 2; ++kk) {
            const int sl = ((kk * 4 + lk) ^ (lr & 7)) * 8;
            short8 a[4], b[4];
#pragma unroll
            for (int f = 0; f < 4; ++f) {
                a[f] = *(const short8*)(As + (wr * 64 + f * 16 + lr) * 64 + sl);
                b[f] = *(const short8*)(Bs + (wc * 64 + f * 16 + lr) * 64 + sl);
            }
#pragma unroll
            for (int fm = 0; fm < 4; ++fm)
#pragma unroll
                for (int fn = 0; fn < 4; ++fn)
                    acc[fm][fn] = __builtin_amdgcn_mfma_f32_16x16x32_bf16(
                        a[fm], b[fn], acc[fm][fn], 0, 0, 0);
        }
    }

#pragma unroll
    for (int fm = 0; fm < 4; ++fm) {
        const int row = m0 + wr * 64 + fm * 16 + lk * 4;
#pragma unroll
        for (int fn = 0; fn < 4; ++fn) {
            const int col = n0 + wc * 64 + fn * 16 + lr;
#pragma unroll
            for (int r2 = 0; r2 < 4; ++r2) {
                Cc[(size_t)(row + r2) * DIMc + col] = f2bf(acc[fm][fn][r2]);
            }
        }
    }
}

// ---------------- combine (+ fused loss in block 0) ----------------
__global__ __launch_bounds__(256) void combine_kernel(
    const u16* __restrict__ eo, const int* __restrict__ slot1, const int* __restrict__ slot2,
    const float* __restrict__ g1, const float* __restrict__ g2, float* __restrict__ out,
    const float* __restrict__ S, const float* __restrict__ Cc, float* __restrict__ loss_dst)
{
    if (blockIdx.x == 0 && threadIdx.x < 64) {
        float v = S[threadIdx.x] * Cc[threadIdx.x];
#pragma unroll
        for (int off = 32; off; off >>= 1) v += __shfl_down(v, off);
        if (threadIdx.x == 0) *loss_dst = v * (0.01f / ((float)Nc * (float)Nc));
    }

    const int tk = blockIdx.x * 4 + (threadIdx.x >> 6);
    const int lane = threadIdx.x & 63;
    int s1 = slot1[tk], s2 = slot2[tk];
    const float a = (s1 >= 0) ? g1[tk] : 0.f;
    const float b = (s2 >= 0) ? g2[tk] : 0.f;
    if (s1 < 0) s1 = 0;
    if (s2 < 0) s2 = 0;
    const uint4* p1 = (const uint4*)(eo + ((size_t)s1 << 10)) + lane * 2;
    const uint4* p2 = (const uint4*)(eo + ((size_t)s2 << 10)) + lane * 2;
    uint4 x0 = p1[0], x1 = p1[1];
    uint4 y0 = p2[0], y1 = p2[1];
    float4* dst = (float4*)(out + ((size_t)tk << 10)) + lane * 4;
    float4 o;
    o.x = a * bflo(x0.x) + b * bflo(y0.x); o.y = a * bfhi(x0.x) + b * bfhi(y0.x);
    o.z = a * bflo(x0.y) + b * bflo(y0.y); o.w = a * bfhi(x0.y) + b * bfhi(y0.y);
    dst[0] = o;
    o.x = a * bflo(x0.z) + b * bflo(y0.z); o.y = a * bfhi(x0.z) + b * bfhi(y0.z);
    o.z = a * bflo(x0.w) + b * bflo(y0.w); o.w = a * bfhi(x0.w) + b * bfhi(y0.w);
    dst[1] = o;
    o.x = a * bflo(x1.x) + b * bflo(y1.x); o.y = a * bfhi(x1.x) + b * bfhi(y1.x);
    o.z = a * bflo(x1.y) + b * bflo(y1.y); o.w = a * bfhi(x1.y) + b * bfhi(y1.y);
    dst[2] = o;
    o.x = a * bflo(x1.z) + b * bflo(y1.z); o.y = a * bfhi(x1.z) + b * bfhi(y1.z);
    o.z = a * bflo(x1.w) + b * bflo(y1.w); o.w = a * bfhi(x1.w) + b * bfhi(y1.w);
    dst[3] = o;
}

// ---------------- launch ----------------
extern "C" void kernel_launch(void* const* d_in, const int* in_sizes, int n_in,
                              void* d_out, int out_size, void* d_ws, size_t ws_size,
                              hipStream_t stream)
{
    (void)in_sizes; (void)n_in; (void)out_size;

    const float* x  = (const float*)d_in[0];
    const float* wg = (const float*)d_in[1];
    const float* w1 = (const float*)d_in[2];
    const float* w2 = (const float*)d_in[3];
    const float* rp = (const float*)d_in[4];
    float* out = (float*)d_out;
    char* ws = (char*)d_ws;

    int epr = 4;
    while (epr > 1 && layout_need(epr) > ws_size) epr >>= 1;
    if (layout_need(epr) > ws_size) return;

    u16* eo  = (u16*)(ws);
    u16* xbf = (u16*)(ws + SZ_EO);
    u16* w1T = (u16*)(ws + SZ_EO + SZ_XBF);
    u16* w2T = (u16*)(ws + SZ_EO + SZ_XBF + (size_t)epr * SZ_W1T_E);
    u16* hid = (u16*)(ws + SZ_EO + SZ_XBF + (size_t)epr * (SZ_W1T_E + SZ_W2T_E));
    char* misc = ws + SZ_EO + SZ_XBF + (size_t)epr * (SZ_W1T_E + SZ_W2T_E + SZ_HID_E);

    int* slot_token = (int*)(misc + OFF_SLOTTOK);
    float* g1 = (float*)(misc + OFF_G1);
    float* g2 = (float*)(misc + OFF_G2);
    int* meta = (int*)(misc + OFF_META);
    int* s1 = (int*)(misc + OFF_S1);
    int* s2 = (int*)(misc + OFF_S2);
    float* raw = (float*)(misc + OFF_RAW);
    float* Sr = (float*)(misc + OFF_S);
    float* C1 = (float*)(misc + OFF_C);
    u16* zp = (u16*)(misc + OFF_ZP);

    gate_kernel<<<NTOK / 4, 256, 0, stream>>>(x, wg, rp, raw, g1, g2, meta, xbf);
    scan_kernel<<<Bc, 256, 0, stream>>>(meta, g1, g2, raw, slot_token, s1, s2,
                                        Sr, C1, (u32*)zp);

    for (int e0 = 0; e0 < Ec; e0 += epr) {
        transpose_all_kernel<<<dim3(2048, 2 * epr), 256, 0, stream>>>(
            w1, w2, w1T, w2T, e0, epr);

        gemm1_kernel<<<dim3(epr * 32, HIDc / 128), 256, 0, stream>>>(
            xbf, slot_token + e0 * SLOTPE, w1T, hid, zp);
        gemm2_kernel<<<dim3(epr * 32, DIMc / 128), 256, 0, stream>>>(
            hid, w2T, eo + (size_t)e0 * SLOTPE * DIMc);
    }

    combine_kernel<<<NTOK / 4, 256, 0, stream>>>(eo, s1, s2, g1, g2, out, Sr, C1,
                                                 out + (size_t)NTOK * DIMc);
}

// Round 15
// 418.003 us; speedup vs baseline: 1.1281x; 1.0097x over previous
//
#include <hip/hip_runtime.h>
#include <hip/hip_bf16.h>

typedef unsigned short u16;
typedef unsigned int u32;

typedef short short8 __attribute__((ext_vector_type(8)));
typedef float f32x4 __attribute__((ext_vector_type(4)));

// ---------------- problem constants ----------------
constexpr int Bc   = 8;
constexpr int Nc   = 2048;
constexpr int DIMc = 1024;
constexpr int Ec   = 8;
constexpr int HIDc = 2048;
constexpr int CAPc = 512;
constexpr int NTOK   = Bc * Nc;        // 16384
constexpr int SLOTPE = Bc * CAPc;      // 4096 slots per expert
constexpr int NSLOT  = Ec * SLOTPE;    // 32768

// ---------------- misc block layout (relative offsets, 2 MiB) ----------------
constexpr size_t OFF_SLOTTOK = 0;
constexpr size_t OFF_G1      = OFF_SLOTTOK + (size_t)NSLOT * 4;
constexpr size_t OFF_G2      = OFF_G1 + (size_t)NTOK * 4;
constexpr size_t OFF_META    = OFF_G2 + (size_t)NTOK * 4;
constexpr size_t OFF_S1      = OFF_META + (size_t)NTOK * 4;
constexpr size_t OFF_S2      = OFF_S1 + (size_t)NTOK * 4;
constexpr size_t OFF_RAW     = OFF_S2 + (size_t)NTOK * 4;
constexpr size_t OFF_S       = OFF_RAW + (size_t)NTOK * 8 * 4;
constexpr size_t OFF_C       = OFF_S + 64 * 4;
constexpr size_t OFF_ZP      = OFF_C + 64 * 4;          // 2 KiB zero page (1024 bf16)
constexpr size_t MISC_SZ     = 2 << 20;
static_assert(OFF_ZP + 2048 <= MISC_SZ, "misc overflow");

constexpr size_t SZ_W1T_E = (size_t)HIDc * DIMc * 2;    // 4 MiB
constexpr size_t SZ_W2T_E = (size_t)DIMc * HIDc * 2;    // 4 MiB
constexpr size_t SZ_HID_E = (size_t)SLOTPE * HIDc * 2;  // 16 MiB
constexpr size_t SZ_EO    = (size_t)NSLOT * DIMc * 2;   // 64 MiB
constexpr size_t SZ_XBF   = (size_t)NTOK * DIMc * 2;    // 32 MiB

// layout: eo | xbf | per-round {w1T, w2T, hid} | misc
__device__ __host__ inline size_t layout_need(int epr) {
    return SZ_EO + SZ_XBF + (size_t)epr * (SZ_W1T_E + SZ_W2T_E + SZ_HID_E) + MISC_SZ;
}

// ---------------- helpers ----------------
__device__ inline u16 f2bf(float f) {
    u32 u = __float_as_uint(f);
    u32 r = (u + 0x7fffu + ((u >> 16) & 1u)) >> 16;
    return (u16)r;
}
__device__ inline u32 pack2(float lo, float hi) {
    return (u32)f2bf(lo) | ((u32)f2bf(hi) << 16);
}
__device__ inline float bflo(u32 u) { return __uint_as_float(u << 16); }
__device__ inline float bfhi(u32 u) { return __uint_as_float(u & 0xffff0000u); }

// tanh-approx gelu via exp2 (max abs err ~1e-3)
__device__ inline float gelu_fast(float v) {
    const float u = v * (0.7978845608028654f + 0.0356774081363001f * v * v);
    return v / (1.f + __builtin_exp2f(-2.885390081777927f * u));
}

#define GLDS16(gp, lp)                                                          \
    __builtin_amdgcn_global_load_lds(                                          \
        (const __attribute__((address_space(1))) void*)(gp),                   \
        (__attribute__((address_space(3))) void*)(lp), 16, 0, 0)

// ---------------- gating: one wave per token; also emits xbf (bf16 x) ----------------
__global__ __launch_bounds__(256) void gate_kernel(
    const float* __restrict__ x, const float* __restrict__ wg,
    const float* __restrict__ rp, float* __restrict__ raw_out,
    float* __restrict__ g1_out, float* __restrict__ g2_out, int* __restrict__ meta_out,
    u16* __restrict__ xbf)
{
    const int tk   = blockIdx.x * 4 + (threadIdx.x >> 6);
    const int lane = threadIdx.x & 63;
    const float* xr = x + (size_t)tk * DIMc;
    u16* xb = xbf + (size_t)tk * DIMc;

    float acc[8] = {0.f, 0.f, 0.f, 0.f, 0.f, 0.f, 0.f, 0.f};
#pragma unroll
    for (int i = 0; i < 4; ++i) {
        const int d0 = i * 256 + lane * 4;
        float4 xv = *(const float4*)(xr + d0);
        uint2 pk;
        pk.x = pack2(xv.x, xv.y);
        pk.y = pack2(xv.z, xv.w);
        *(uint2*)(xb + d0) = pk;
#pragma unroll
        for (int j = 0; j < 4; ++j) {
            float xs = (&xv.x)[j];
            float4 w0 = *(const float4*)(wg + (size_t)(d0 + j) * 8);
            float4 w1 = *(const float4*)(wg + (size_t)(d0 + j) * 8 + 4);
            acc[0] += xs * w0.x; acc[1] += xs * w0.y; acc[2] += xs * w0.z; acc[3] += xs * w0.w;
            acc[4] += xs * w1.x; acc[5] += xs * w1.y; acc[6] += xs * w1.z; acc[7] += xs * w1.w;
        }
    }
#pragma unroll
    for (int e = 0; e < 8; ++e) {
#pragma unroll
        for (int off = 1; off < 64; off <<= 1) acc[e] += __shfl_xor(acc[e], off);
    }

    if (lane == 0) {
        float mx = acc[0];
#pragma unroll
        for (int e = 1; e < 8; ++e) mx = fmaxf(mx, acc[e]);
        float ex[8], s = 0.f;
#pragma unroll
        for (int e = 0; e < 8; ++e) { ex[e] = expf(acc[e] - mx); s += ex[e]; }
        float inv = 1.f / s;
        float raw[8];
#pragma unroll
        for (int e = 0; e < 8; ++e) raw[e] = ex[e] * inv;

        int i1 = 0; float g1 = raw[0];
#pragma unroll
        for (int e = 1; e < 8; ++e) if (raw[e] > g1) { g1 = raw[e]; i1 = e; }
        int i2 = -1; float g2 = -1.f;
#pragma unroll
        for (int e = 0; e < 8; ++e) if (e != i1 && raw[e] > g2) { g2 = raw[e]; i2 = e; }

        float denom = g1 + g2 + 1e-9f;
        float g1n = g1 / denom, g2n = g2 / denom;
        int keep = (rp[tk] < (g2n / 0.2f)) ? 1 : 0;

        float* ro = raw_out + (size_t)tk * 8;
#pragma unroll
        for (int e = 0; e < 8; ++e) ro[e] = raw[e];
        g1_out[tk] = g1n;
        g2_out[tk] = g2n;
        meta_out[tk] = i1 | (i2 << 4) | (keep << 8);
    }
}

// ---------------- per-batch capacity scan + fused loss stats (parallel prefix) ----------------
// Hillis-Steele inclusive scans over 256 threads (8 expert lanes each) replace the
// 256-iteration serial loops. Assignment order identical to serial version
// (thread order == token order). Also inits slot map slice + zero page.
__global__ __launch_bounds__(256) void scan_kernel(
    const int* __restrict__ meta, const float* __restrict__ raw,
    int* __restrict__ slot_token, int* __restrict__ slot1, int* __restrict__ slot2,
    float* __restrict__ S, float* __restrict__ Cc, u32* __restrict__ zp)
{
    const int b = blockIdx.x;
    const int t = threadIdx.x;
    __shared__ int cnt[256][8];
    __shared__ float psum[256][8];

    // fold-in: init this block's slot slice (batch b, all experts) + zero page
#pragma unroll
    for (int j = 0; j < 16; ++j) {
        const int idx = t * 16 + j;                       // e*512 + pos
        slot_token[(((idx >> 9) * Bc + b) << 9) | (idx & 511)] = -1;
    }
    if (b == 0) { zp[t * 2] = 0u; zp[t * 2 + 1] = 0u; }   // 512 u32 = 1024 bf16

    int m[8];
#pragma unroll
    for (int i = 0; i < 8; ++i) m[i] = meta[b * Nc + t * 8 + i];

    // raw sums for this thread's 8 tokens (contiguous 64 floats -> coalesced)
    {
        float rs[8] = {0.f, 0.f, 0.f, 0.f, 0.f, 0.f, 0.f, 0.f};
        const float* rbase = raw + ((size_t)(b * Nc + t * 8)) * 8;
#pragma unroll
        for (int i = 0; i < 8; ++i) {
            float4 lo = *(const float4*)(rbase + i * 8);
            float4 hi = *(const float4*)(rbase + i * 8 + 4);
            rs[0] += lo.x; rs[1] += lo.y; rs[2] += lo.z; rs[3] += lo.w;
            rs[4] += hi.x; rs[5] += hi.y; rs[6] += hi.z; rs[7] += hi.w;
        }
#pragma unroll
        for (int e = 0; e < 8; ++e) psum[t][e] = rs[e];
    }

    // ---- phase 1: first expert ----
    int own[8] = {0, 0, 0, 0, 0, 0, 0, 0};
#pragma unroll
    for (int i = 0; i < 8; ++i) own[m[i] & 15]++;
#pragma unroll
    for (int e = 0; e < 8; ++e) cnt[t][e] = own[e];
    __syncthreads();

    // Hillis-Steele inclusive scan on cnt (+ psum totals ride along)
    for (int off = 1; off < 256; off <<= 1) {
        int v[8]; float pv[8];
        const bool act = (t >= off);
        if (act) {
#pragma unroll
            for (int e = 0; e < 8; ++e) { v[e] = cnt[t - off][e]; pv[e] = psum[t - off][e]; }
        }
        __syncthreads();
        if (act) {
#pragma unroll
            for (int e = 0; e < 8; ++e) { cnt[t][e] += v[e]; psum[t][e] += pv[e]; }
        }
        __syncthreads();
    }

    // totals + per-thread exclusive prefix (registers) before cnt reuse
    int basec[8], c[8];
#pragma unroll
    for (int e = 0; e < 8; ++e) {
        const int tot = cnt[255][e];
        basec[e] = tot < CAPc ? tot : CAPc;
        c[e] = cnt[t][e] - own[e];
    }
    if (t < 8) {
        Cc[b * 8 + t] = (float)cnt[255][t];   // uncapped count = density_1 * Nc
        S[b * 8 + t]  = psum[255][t];
    }

#pragma unroll
    for (int i = 0; i < 8; ++i) {
        const int tk = b * Nc + t * 8 + i;
        const int e = m[i] & 15;
        const int pos = c[e]++;
        if (pos < CAPc) {
            const int slot = ((e * Bc + b) << 9) | pos;
            slot_token[slot] = tk;
            slot1[tk] = slot;
        } else {
            slot1[tk] = -1;
        }
    }
    __syncthreads();

    // ---- phase 2: second expert ----
    int own2[8] = {0, 0, 0, 0, 0, 0, 0, 0};
#pragma unroll
    for (int i = 0; i < 8; ++i) {
        if ((m[i] >> 8) & 1) own2[(m[i] >> 4) & 15]++;
    }
#pragma unroll
    for (int e = 0; e < 8; ++e) cnt[t][e] = own2[e];
    __syncthreads();

    for (int off = 1; off < 256; off <<= 1) {
        int v[8];
        const bool act = (t >= off);
        if (act) {
#pragma unroll
            for (int e = 0; e < 8; ++e) v[e] = cnt[t - off][e];
        }
        __syncthreads();
        if (act) {
#pragma unroll
            for (int e = 0; e < 8; ++e) cnt[t][e] += v[e];
        }
        __syncthreads();
    }

#pragma unroll
    for (int e = 0; e < 8; ++e) c[e] = cnt[t][e] - own2[e];
#pragma unroll
    for (int i = 0; i < 8; ++i) {
        const int tk = b * Nc + t * 8 + i;
        int s2v = -1;
        if ((m[i] >> 8) & 1) {
            const int e = (m[i] >> 4) & 15;
            const int pos = basec[e] + c[e]++;
            if (pos < CAPc) {
                const int slot = ((e * Bc + b) << 9) | pos;
                slot_token[slot] = tk;
                s2v = slot;
            }
        }
        slot2[tk] = s2v;
    }
}

// ---------------- merged weight transpose + bf16 convert (w1 & w2 in one launch) ----------------
__global__ __launch_bounds__(256) void transpose_all_kernel(
    const float* __restrict__ w1, const float* __restrict__ w2,
    u16* __restrict__ w1T, u16* __restrict__ w2T, const int e0, const int epr)
{
    __shared__ float tile[32][33];
    const int z = blockIdx.y;
    const bool is1 = z < epr;
    const int ez = is1 ? z : z - epr;
    const int R = is1 ? DIMc : HIDc;
    const int C = is1 ? HIDc : DIMc;
    const int xmask = (C / 32) - 1;
    const int xshift = is1 ? 6 : 5;
    const int blk = blockIdx.x;
    const int c0 = (blk & xmask) * 32, r0 = (blk >> xshift) * 32;
    const float* src = (is1 ? w1 : w2) + (size_t)(e0 + ez) * R * C;
    u16* dst = (is1 ? w1T : w2T) + (size_t)ez * C * R;
    const int t = threadIdx.x;
#pragma unroll
    for (int i = 0; i < 4; ++i) {
        const int r = i * 8 + (t >> 5), cc = t & 31;
        tile[r][cc] = src[(size_t)(r0 + r) * C + c0 + cc];
    }
    __syncthreads();
#pragma unroll
    for (int i = 0; i < 4; ++i) {
        const int cc = i * 8 + (t >> 5), r = t & 31;
        dst[(size_t)(c0 + cc) * R + r0 + r] = f2bf(tile[r][cc]);
    }
}

// ---------------- tile swizzle helper (XCD chunk + GN=4 n-grouping) ----------------
__device__ inline void tile_swizzle(int& mt, int& nt) {
    const int MT = gridDim.x;
    const int lin = blockIdx.y * MT + blockIdx.x;
    const int nb  = MT * gridDim.y;
    const int per = nb >> 3;
    const int sid = (lin & 7) * per + (lin >> 3);
    const int gsz = MT << 2;
    const int g   = sid / gsz;
    const int r   = sid - g * gsz;
    mt = r >> 2;
    nt = (g << 2) + (r & 3);
}

// ---------------- gemm1: A = xbf rows via slot_token indirection (gather fused) ----------------
__global__ __launch_bounds__(256, 4) void gemm1_kernel(
    const u16* __restrict__ xbf, const int* __restrict__ slot_tok_round,
    const u16* __restrict__ Bt, u16* __restrict__ Cc, const u16* __restrict__ zp)
{
    constexpr int K = DIMc;
    __shared__ u16 As[128 * 64];
    __shared__ u16 Bs[128 * 64];

    const int tid = threadIdx.x;
    const int wv = tid >> 6, lane = tid & 63;

    int mt, nt;
    tile_swizzle(mt, nt);
    const int m0 = mt * 128, n0 = nt * 128;
    const int e = mt >> 5;

    const int wr = wv >> 1, wc = wv & 1;
    const int lr = lane & 15, lk = lane >> 4;

    const int rb = tid >> 3;
    const int gc = (((tid & 7) ^ ((tid >> 3) & 7)) * 8);

    const u16* pa[4];
#pragma unroll
    for (int p = 0; p < 4; ++p) {
        const int tk = slot_tok_round[m0 + rb + 32 * p];
        pa[p] = ((tk >= 0) ? xbf + ((size_t)tk << 10) : zp) + gc;
    }
    const u16* pbb = Bt + ((size_t)e * HIDc + n0 + rb) * K + gc;
    const u16* pb1 = pbb + (size_t)32 * K;
    const u16* pb2 = pbb + (size_t)64 * K;
    const u16* pb3 = pbb + (size_t)96 * K;

    u16* la = As + tid * 8;
    u16* lb = Bs + tid * 8;

    f32x4 acc[4][4];
#pragma unroll
    for (int i = 0; i < 4; ++i)
#pragma unroll
        for (int j = 0; j < 4; ++j) acc[i][j] = (f32x4)0.f;

    for (int k0 = 0; k0 < K; k0 += 64) {
        __syncthreads();
        GLDS16(pa[0], la);        GLDS16(pa[1], la + 2048);
        GLDS16(pa[2], la + 4096); GLDS16(pa[3], la + 6144);
        GLDS16(pbb, lb);          GLDS16(pb1, lb + 2048);
        GLDS16(pb2, lb + 4096);   GLDS16(pb3, lb + 6144);
#pragma unroll
        for (int p = 0; p < 4; ++p) pa[p] += 64;
        pbb += 64; pb1 += 64; pb2 += 64; pb3 += 64;
        __syncthreads();

#pragma unroll
        for (int kk = 0; kk < 2; ++kk) {
            const int sl = ((kk * 4 + lk) ^ (lr & 7)) * 8;
            short8 a[4], b[4];
#pragma unroll
            for (int f = 0; f < 4; ++f) {
                a[f] = *(const short8*)(As + (wr * 64 + f * 16 + lr) * 64 + sl);
                b[f] = *(const short8*)(Bs + (wc * 64 + f * 16 + lr) * 64 + sl);
            }
#pragma unroll
            for (int fm = 0; fm < 4; ++fm)
#pragma unroll
                for (int fn = 0; fn < 4; ++fn)
                    acc[fm][fn] = __builtin_amdgcn_mfma_f32_16x16x32_bf16(
                        a[fm], b[fn], acc[fm][fn], 0, 0, 0);
        }
    }

#pragma unroll
    for (int fm = 0; fm < 4; ++fm) {
        const int row = m0 + wr * 64 + fm * 16 + lk * 4;
#pragma unroll
        for (int fn = 0; fn < 4; ++fn) {
            const int col = n0 + wc * 64 + fn * 16 + lr;
#pragma unroll
            for (int r2 = 0; r2 < 4; ++r2) {
                Cc[(size_t)(row + r2) * HIDc + col] = f2bf(gelu_fast(acc[fm][fn][r2]));
            }
        }
    }
}

// ---------------- gemm2: round-11 body verbatim (plain bf16 store) ----------------
__global__ __launch_bounds__(256, 4) void gemm2_kernel(
    const u16* __restrict__ A, const u16* __restrict__ Bt, u16* __restrict__ Cc)
{
    constexpr int K = HIDc;
    __shared__ u16 As[128 * 64];
    __shared__ u16 Bs[128 * 64];

    const int tid = threadIdx.x;
    const int wv = tid >> 6, lane = tid & 63;

    int mt, nt;
    tile_swizzle(mt, nt);
    const int m0 = mt * 128, n0 = nt * 128;
    const int e = mt >> 5;

    const int wr = wv >> 1, wc = wv & 1;
    const int lr = lane & 15, lk = lane >> 4;

    const int rb = tid >> 3;
    const int gc = (((tid & 7) ^ ((tid >> 3) & 7)) * 8);

    const u16* pa0 = A + (size_t)(m0 + rb) * K + gc;
    const u16* pa1 = pa0 + (size_t)32 * K;
    const u16* pa2 = pa0 + (size_t)64 * K;
    const u16* pa3 = pa0 + (size_t)96 * K;
    const u16* pbb = Bt + ((size_t)e * DIMc + n0 + rb) * K + gc;
    const u16* pb1 = pbb + (size_t)32 * K;
    const u16* pb2 = pbb + (size_t)64 * K;
    const u16* pb3 = pbb + (size_t)96 * K;

    u16* la = As + tid * 8;
    u16* lb = Bs + tid * 8;

    f32x4 acc[4][4];
#pragma unroll
    for (int i = 0; i < 4; ++i)
#pragma unroll
        for (int j = 0; j < 4; ++j) acc[i][j] = (f32x4)0.f;

    for (int k0 = 0; k0 < K; k0 += 64) {
        __syncthreads();
        GLDS16(pa0, la);        GLDS16(pa1, la + 2048);
        GLDS16(pa2, la + 4096); GLDS16(pa3, la + 6144);
        GLDS16(pbb, lb);        GLDS16(pb1, lb + 2048);
        GLDS16(pb2, lb + 4096); GLDS16(pb3, lb + 6144);
        pa0 += 64; pa1 += 64; pa2 += 64; pa3 += 64;
        pbb += 64; pb1 += 64; pb2 += 64; pb3 += 64;
        __syncthreads();

#pragma unroll
        for (int kk = 0; kk < 2; ++kk) {
            const int sl = ((kk * 4 + lk) ^ (lr & 7)) * 8;
            short8 a[4], b[4];
#pragma unroll
            for (int f = 0; f < 4; ++f) {
                a[f] = *(const short8*)(As + (wr * 64 + f * 16 + lr) * 64 + sl);
                b[f] = *(const short8*)(Bs + (wc * 64 + f * 16 + lr) * 64 + sl);
            }
#pragma unroll
            for (int fm = 0; fm < 4; ++fm)
#pragma unroll
                for (int fn = 0; fn < 4; ++fn)
                    acc[fm][fn] = __builtin_amdgcn_mfma_f32_16x16x32_bf16(
                        a[fm], b[fn], acc[fm][fn], 0, 0, 0);
        }
    }

#pragma unroll
    for (int fm = 0; fm < 4; ++fm) {
        const int row = m0 + wr * 64 + fm * 16 + lk * 4;
#pragma unroll
        for (int fn = 0; fn < 4; ++fn) {
            const int col = n0 + wc * 64 + fn * 16 + lr;
#pragma unroll
            for (int r2 = 0; r2 < 4; ++r2) {
                Cc[(size_t)(row + r2) * DIMc + col] = f2bf(acc[fm][fn][r2]);
            }
        }
    }
}

// ---------------- combine (+ fused loss in block 0) ----------------
__global__ __launch_bounds__(256) void combine_kernel(
    const u16* __restrict__ eo, const int* __restrict__ slot1, const int* __restrict__ slot2,
    const float* __restrict__ g1, const float* __restrict__ g2, float* __restrict__ out,
    const float* __restrict__ S, const float* __restrict__ Cc, float* __restrict__ loss_dst)
{
    if (blockIdx.x == 0 && threadIdx.x < 64) {
        float v = S[threadIdx.x] * Cc[threadIdx.x];
#pragma unroll
        for (int off = 32; off; off >>= 1) v += __shfl_down(v, off);
        if (threadIdx.x == 0) *loss_dst = v * (0.01f / ((float)Nc * (float)Nc));
    }

    const int tk = blockIdx.x * 4 + (threadIdx.x >> 6);
    const int lane = threadIdx.x & 63;
    int s1 = slot1[tk], s2 = slot2[tk];
    const float a = (s1 >= 0) ? g1[tk] : 0.f;
    const float b = (s2 >= 0) ? g2[tk] : 0.f;
    if (s1 < 0) s1 = 0;
    if (s2 < 0) s2 = 0;
    const uint4* p1 = (const uint4*)(eo + ((size_t)s1 << 10)) + lane * 2;
    const uint4* p2 = (const uint4*)(eo + ((size_t)s2 << 10)) + lane * 2;
    uint4 x0 = p1[0], x1 = p1[1];
    uint4 y0 = p2[0], y1 = p2[1];
    float4* dst = (float4*)(out + ((size_t)tk << 10)) + lane * 4;
    float4 o;
    o.x = a * bflo(x0.x) + b * bflo(y0.x); o.y = a * bfhi(x0.x) + b * bfhi(y0.x);
    o.z = a * bflo(x0.y) + b * bflo(y0.y); o.w = a * bfhi(x0.y) + b * bfhi(y0.y);
    dst[0] = o;
    o.x = a * bflo(x0.z) + b * bflo(y0.z); o.y = a * bfhi(x0.z) + b * bfhi(y0.z);
    o.z = a * bflo(x0.w) + b * bflo(y0.w); o.w = a * bfhi(x0.w) + b * bfhi(y0.w);
    dst[1] = o;
    o.x = a * bflo(x1.x) + b * bflo(y1.x); o.y = a * bfhi(x1.x) + b * bfhi(y1.x);
    o.z = a * bflo(x1.y) + b * bflo(y1.y); o.w = a * bfhi(x1.y) + b * bfhi(y1.y);
    dst[2] = o;
    o.x = a * bflo(x1.z) + b * bflo(y1.z); o.y = a * bfhi(x1.z) + b * bfhi(y1.z);
    o.z = a * bflo(x1.w) + b * bflo(y1.w); o.w = a * bfhi(x1.w) + b * bfhi(y1.w);
    dst[3] = o;
}

// ---------------- launch ----------------
extern "C" void kernel_launch(void* const* d_in, const int* in_sizes, int n_in,
                              void* d_out, int out_size, void* d_ws, size_t ws_size,
                              hipStream_t stream)
{
    (void)in_sizes; (void)n_in; (void)out_size;

    const float* x  = (const float*)d_in[0];
    const float* wg = (const float*)d_in[1];
    const float* w1 = (const float*)d_in[2];
    const float* w2 = (const float*)d_in[3];
    const float* rp = (const float*)d_in[4];
    float* out = (float*)d_out;
    char* ws = (char*)d_ws;

    int epr = 4;
    while (epr > 1 && layout_need(epr) > ws_size) epr >>= 1;
    if (layout_need(epr) > ws_size) return;

    u16* eo  = (u16*)(ws);
    u16* xbf = (u16*)(ws + SZ_EO);
    u16* w1T = (u16*)(ws + SZ_EO + SZ_XBF);
    u16* w2T = (u16*)(ws + SZ_EO + SZ_XBF + (size_t)epr * SZ_W1T_E);
    u16* hid = (u16*)(ws + SZ_EO + SZ_XBF + (size_t)epr * (SZ_W1T_E + SZ_W2T_E));
    char* misc = ws + SZ_EO + SZ_XBF + (size_t)epr * (SZ_W1T_E + SZ_W2T_E + SZ_HID_E);

    int* slot_token = (int*)(misc + OFF_SLOTTOK);
    float* g1 = (float*)(misc + OFF_G1);
    float* g2 = (float*)(misc + OFF_G2);
    int* meta = (int*)(misc + OFF_META);
    int* s1 = (int*)(misc + OFF_S1);
    int* s2 = (int*)(misc + OFF_S2);
    float* raw = (float*)(misc + OFF_RAW);
    float* Sr = (float*)(misc + OFF_S);
    float* C1 = (float*)(misc + OFF_C);
    u16* zp = (u16*)(misc + OFF_ZP);

    gate_kernel<<<NTOK / 4, 256, 0, stream>>>(x, wg, rp, raw, g1, g2, meta, xbf);
    scan_kernel<<<Bc, 256, 0, stream>>>(meta, raw, slot_token, s1, s2, Sr, C1, (u32*)zp);

    for (int e0 = 0; e0 < Ec; e0 += epr) {
        transpose_all_kernel<<<dim3(2048, 2 * epr), 256, 0, stream>>>(
            w1, w2, w1T, w2T, e0, epr);

        gemm1_kernel<<<dim3(epr * 32, HIDc / 128), 256, 0, stream>>>(
            xbf, slot_token + e0 * SLOTPE, w1T, hid, zp);
        gemm2_kernel<<<dim3(epr * 32, DIMc / 128), 256, 0, stream>>>(
            hid, w2T, eo + (size_t)e0 * SLOTPE * DIMc);
    }

    combine_kernel<<<NTOK / 4, 256, 0, stream>>>(eo, s1, s2, g1, g2, out, Sr, C1,
                                                 out + (size_t)NTOK * DIMc);
}